// Round 12
// baseline (150.331 us; speedup 1.0000x reference)
//
#include <hip/hip_runtime.h>

// ---------------------------------------------------------------------------
// MultiHeadAttention forward, MI355X (gfx950), bf16 MFMA pipeline. Round 12:
//  - attn: QBLK=256 (4 waves x 64 q-rows/wave) -> halves LDS b128 reads per
//    MFMA (R11 model: LDS throughput-bound at 3840cy vs MFMA 2500cy per kt).
//    Grid 256 (1 block/CU), LDS 96KB, KBLK=128 (2x64 halves), XCD swizzle.
//  - mask_allones folded into cvt_all (blockIdx.y==7 slice).
//  - GEMMs: proven 128x64x64 dbuf (48KB, 1536/512 grids).
// ---------------------------------------------------------------------------

typedef __attribute__((ext_vector_type(4))) float  f32x4;
typedef __attribute__((ext_vector_type(8))) __bf16 bf16x8;
typedef __attribute__((ext_vector_type(4))) __bf16 bf16x4;

#define SLEN 2048
#define BSZ  2
#define DMODEL 1024
#define NHEAD 16
#define DHEAD 64
#define D3 (3 * DMODEL)   // 3072

__device__ __forceinline__ void async16(void* lds, const void* g) {
    __builtin_amdgcn_global_load_lds(
        (const __attribute__((address_space(1))) unsigned int*)g,
        (__attribute__((address_space(3))) unsigned int*)lds, 16, 0, 0);
}

__device__ __forceinline__ f32x4 mfma16(bf16x8 a, bf16x8 b, f32x4 c) {
    return __builtin_amdgcn_mfma_f32_16x16x32_bf16(a, b, c, 0, 0, 0);
}

// ------------------- fused convert fp32 -> bf16 (+ mask flag) --------------
struct CvtArgs {
    const float* src[7];
    __bf16* dst[7];
    int n4[7];
    float scale[7];
    const int* mask;
    unsigned int* flag;
    int maskn4;
};
__global__ void cvt_all(CvtArgs a) {
    const int t = blockIdx.y;
    const int stride = gridDim.x * blockDim.x;
    if (t == 7) {
        bool ok = true;
        for (int i = blockIdx.x * blockDim.x + threadIdx.x; i < a.maskn4; i += stride) {
            int4 v = ((const int4*)a.mask)[i];
            ok = ok && v.x && v.y && v.z && v.w;
        }
        if (!ok) atomicAnd(a.flag, 0u);
        return;
    }
    const float* __restrict__ src = a.src[t];
    __bf16* __restrict__ dst = a.dst[t];
    const int n4 = a.n4[t];
    const float sc = a.scale[t];
    for (int i = blockIdx.x * blockDim.x + threadIdx.x; i < n4; i += stride) {
        float4 v = ((const float4*)src)[i];
        bf16x4 o;
        o[0] = (__bf16)(v.x * sc); o[1] = (__bf16)(v.y * sc);
        o[2] = (__bf16)(v.z * sc); o[3] = (__bf16)(v.w * sc);
        ((bf16x4*)dst)[i] = o;
    }
}

// ---------------------------- GEMM core: 128x64x64 dbuf --------------------
template <typename CT>
__device__ __forceinline__ void gemm_core(const char* Ab, const char* Bb, int K,
                                          CT* Cv, size_t crow0, size_t ccol0,
                                          size_t ldc) {
    __shared__ __bf16 At[2][128 * 64];
    __shared__ __bf16 Bt[2][64 * 64];
    const int tid = threadIdx.x;
    const int lane = tid & 63, wv = tid >> 6;
    const int l15 = lane & 15, l4 = lane >> 4;
    const int wr = wv >> 1, wc = wv & 1;
    const int srow = lane >> 3;
    const int sbyte = (((lane & 7) ^ srow) << 4);

    f32x4 acc[4][2];
#pragma unroll
    for (int m = 0; m < 4; m++)
#pragma unroll
        for (int n = 0; n < 2; n++)
#pragma unroll
            for (int r = 0; r < 4; r++) acc[m][n][r] = 0.0f;

    auto stage = [&](int buf, int k0) {
#pragma unroll
        for (int i = 0; i < 6; i++) {
            int c = wv * 6 + i;
            if (c < 16) {
                int row = c * 8 + srow;
                async16(&At[buf][c * 512], Ab + ((size_t)row * K + k0) * 2 + sbyte);
            } else {
                int row = (c - 16) * 8 + srow;
                async16(&Bt[buf][(c - 16) * 512], Bb + ((size_t)row * K + k0) * 2 + sbyte);
            }
        }
    };

    stage(0, 0);
    __syncthreads();
    int cur = 0;
    for (int k0 = 0; k0 < K; k0 += 64) {
        if (k0 + 64 < K) stage(cur ^ 1, k0 + 64);
#pragma unroll
        for (int kk = 0; kk < 2; kk++) {
            bf16x8 af[4], bfr[2];
#pragma unroll
            for (int m = 0; m < 4; m++) {
                int row = wr * 64 + m * 16 + l15;
                int col = (kk * 32 + l4 * 8) ^ ((row & 7) << 3);
                af[m] = *(const bf16x8*)&At[cur][row * 64 + col];
            }
#pragma unroll
            for (int n = 0; n < 2; n++) {
                int row = wc * 32 + n * 16 + l15;
                int col = (kk * 32 + l4 * 8) ^ ((row & 7) << 3);
                bfr[n] = *(const bf16x8*)&Bt[cur][row * 64 + col];
            }
#pragma unroll
            for (int m = 0; m < 4; m++)
#pragma unroll
                for (int n = 0; n < 2; n++)
                    acc[m][n] = mfma16(af[m], bfr[n], acc[m][n]);
        }
        __syncthreads();
        cur ^= 1;
    }

#pragma unroll
    for (int m = 0; m < 4; m++)
#pragma unroll
        for (int n = 0; n < 2; n++)
#pragma unroll
            for (int r = 0; r < 4; r++) {
                size_t row = crow0 + wr * 64 + m * 16 + l4 * 4 + r;
                size_t col = ccol0 + wc * 32 + n * 16 + l15;
                Cv[row * ldc + col] = (CT)acc[m][n][r];
            }
}

// fused QKV projection: C[4096][3072] = A_sel @ W[3072][1024]^T, bn 0..47
__global__ __launch_bounds__(256, 2) void gemm_qkv(const __bf16* __restrict__ Xq,
                                                   const __bf16* __restrict__ Xk,
                                                   const __bf16* __restrict__ Xv,
                                                   const __bf16* __restrict__ W,
                                                   __bf16* __restrict__ C) {
    const int bm = blockIdx.x, bn = blockIdx.y;
    const __bf16* A = (bn < 16) ? Xq : (bn < 32) ? Xk : Xv;
    gemm_core<__bf16>((const char*)(A + (size_t)bm * 128 * DMODEL),
                      (const char*)(W + (size_t)bn * 64 * DMODEL), DMODEL,
                      C, (size_t)bm * 128, (size_t)bn * 64, D3);
}

// out GEMM: out[4096][1024] = ATT @ Wo^T, fp32 out, bn 0..15
__global__ __launch_bounds__(256, 2) void gemm_out(const __bf16* __restrict__ A,
                                                   const __bf16* __restrict__ B,
                                                   float* __restrict__ Cv) {
    const int bm = blockIdx.x, bn = blockIdx.y;
    gemm_core<float>((const char*)(A + (size_t)bm * 128 * DMODEL),
                     (const char*)(B + (size_t)bn * 64 * DMODEL), DMODEL,
                     Cv, (size_t)bm * 128, (size_t)bn * 64, DMODEL);
}

// ---------------------------- V transpose ----------------------------------
__global__ __launch_bounds__(256) void transpose_v(const __bf16* __restrict__ QKV,
                                                   __bf16* __restrict__ Vt) {
    __shared__ __bf16 t[64][72];
    const int stile = blockIdx.x;
    const int bh = blockIdx.y;
    const int b = bh >> 4, h = bh & 15;
    const int tid = threadIdx.x;
    {
        int sr = tid >> 2, d0 = (tid & 3) * 16;
        const __bf16* src = QKV + ((size_t)((stile * 64 + sr) * BSZ + b) * D3 + 2 * DMODEL + h * 64 + d0);
        *(bf16x8*)&t[sr][d0]     = *(const bf16x8*)src;
        *(bf16x8*)&t[sr][d0 + 8] = *(const bf16x8*)(src + 8);
    }
    __syncthreads();
    {
        int d = tid >> 2, s0 = (tid & 3) * 16;
        bf16x8 o1, o2;
#pragma unroll
        for (int j = 0; j < 8; j++) { o1[j] = t[s0 + j][d]; o2[j] = t[s0 + 8 + j][d]; }
        __bf16* dst = Vt + ((size_t)(bh * 64 + d) * SLEN + stile * 64 + s0);
        *(bf16x8*)dst = o1;
        *(bf16x8*)(dst + 8) = o2;
    }
}

// ---------------------------- attention ------------------------------------
// grid 256 (32 bh x 8 qt), XCD swizzle: blk&7 -> xcd; 4 bh x 8 qt per XCD.
// QBLK=256: 4 waves x 64 q-rows. KBLK=128 staged (2x64 halves), dbuf.
__global__ __launch_bounds__(256, 1) void attn_fwd(const __bf16* __restrict__ QKV,
                                                   const __bf16* __restrict__ Vt,
                                                   const int* __restrict__ mask,
                                                   const unsigned int* __restrict__ flag,
                                                   __bf16* __restrict__ Attn) {
    __shared__ __bf16 Kt[2][2][64 * 64];   // [buf][kh][k][d]  32 KB
    __shared__ __bf16 Vs[2][2][64 * 64];   // [buf][kh][d][k]  32 KB
    __shared__ __bf16 Ps[256 * 64];        // [q][k64] wave-private rows, 32 KB
    const int tid = threadIdx.x;
    const int lane = tid & 63, wv = tid >> 6;
    const int l15 = lane & 15, l4 = lane >> 4;
    // XCD swizzle: 256 blocks, 8 XCDs, 32 blocks/XCD = 4 bh x 8 qt
    const int blk = blockIdx.x;
    const int xcd = blk & 7, idx = blk >> 3;
    const int bh = xcd + (idx >> 3) * 8;
    const int qt = idx & 7;
    const int b = bh >> 4, h = bh & 15;
    const bool allones = (*flag != 0u);
    const int srow = lane >> 3;
    const int sbyte = (((lane & 7) ^ srow) << 4);

    // Q fragments in registers (per wave: 64 rows x 64 d)
    bf16x8 aq[4][2];
#pragma unroll
    for (int m = 0; m < 4; m++)
#pragma unroll
        for (int kk = 0; kk < 2; kk++) {
            int qrow = qt * 256 + wv * 64 + m * 16 + l15;
            aq[m][kk] = *(const bf16x8*)(QKV + ((size_t)(qrow * BSZ + b) * D3 + h * 64 + kk * 32 + l4 * 8));
        }

    f32x4 o[4][4], lr[4];
#pragma unroll
    for (int m = 0; m < 4; m++) {
#pragma unroll
        for (int nd = 0; nd < 4; nd++)
#pragma unroll
            for (int r = 0; r < 4; r++) o[m][nd][r] = 0.0f;
#pragma unroll
        for (int r = 0; r < 4; r++) lr[m][r] = 0.0f;
    }

    const char* Kb = (const char*)QKV + ((size_t)b * D3 + DMODEL + h * 64) * 2;
    const char* Vb = (const char*)Vt + ((size_t)bh * 64) * SLEN * 2;

    // stage one 128-k tile: 16 K chunks + 16 V chunks over 4 waves
    auto stage = [&](int buf, int kt) {
#pragma unroll
        for (int i = 0; i < 8; i++) {
            int c = wv * 8 + i;  // 0..31
            if (c < 16) {
                int kh = c >> 3, ck = c & 7;
                int krow = kt * 128 + kh * 64 + ck * 8 + srow;
                async16(&Kt[buf][kh][ck * 512],
                        Kb + (size_t)krow * (BSZ * D3 * 2) + sbyte);
            } else {
                int c2 = c - 16;
                int kh = c2 >> 3, ck = c2 & 7;
                int drow = ck * 8 + srow;
                async16(&Vs[buf][kh][ck * 512],
                        Vb + (size_t)drow * (SLEN * 2) + kt * 256 + kh * 128 + sbyte);
            }
        }
    };

    stage(0, 0);
    __syncthreads();
    int cur = 0;

    for (int kt = 0; kt < SLEN / 128; kt++) {
        if (kt + 1 < SLEN / 128) stage(cur ^ 1, kt + 1);

#pragma unroll
        for (int kh = 0; kh < 2; kh++) {
            const __bf16* Kl = Kt[cur][kh];
            const __bf16* Vl = Vs[cur][kh];

            // hoist K fragments (shared across the 4 m-tiles)
            bf16x8 bk[4][2];
#pragma unroll
            for (int n = 0; n < 4; n++) {
                int row = n * 16 + l15;
#pragma unroll
                for (int kk = 0; kk < 2; kk++) {
                    int col = (kk * 32 + l4 * 8) ^ ((row & 7) << 3);
                    bk[n][kk] = *(const bf16x8*)&Kl[row * 64 + col];
                }
            }

            // per m-tile: S = Q K^T -> mask -> exp2 -> Ps (s regs reused)
#pragma unroll
            for (int m = 0; m < 4; m++) {
                f32x4 s[4];
#pragma unroll
                for (int n = 0; n < 4; n++)
#pragma unroll
                    for (int r = 0; r < 4; r++) s[n][r] = 0.0f;
                __builtin_amdgcn_s_setprio(1);
#pragma unroll
                for (int n = 0; n < 4; n++)
#pragma unroll
                    for (int kk = 0; kk < 2; kk++)
                        s[n] = mfma16(aq[m][kk], bk[n][kk], s[n]);
                __builtin_amdgcn_s_setprio(0);

                if (!allones) {
#pragma unroll
                    for (int n = 0; n < 4; n++)
#pragma unroll
                        for (int r = 0; r < 4; r++) {
                            int q = qt * 256 + wv * 64 + m * 16 + l4 * 4 + r;
                            int kg = kt * 128 + kh * 64 + n * 16 + l15;
                            if (mask[(size_t)q * SLEN + kg] == 0) s[n][r] = -1e20f;
                        }
                }

#pragma unroll
                for (int n = 0; n < 4; n++)
#pragma unroll
                    for (int r = 0; r < 4; r++) {
                        float p = __builtin_amdgcn_exp2f(s[n][r]);
                        lr[m][r] += p;
                        int row = wv * 64 + m * 16 + l4 * 4 + r;
                        int col = (n * 16 + l15) ^ ((row & 7) << 3);
                        Ps[row * 64 + col] = (__bf16)p;
                    }
            }

            // O += P V
            __builtin_amdgcn_s_setprio(1);
#pragma unroll
            for (int ks = 0; ks < 2; ks++) {
                bf16x8 ap[4];
#pragma unroll
                for (int m = 0; m < 4; m++) {
                    int prow = wv * 64 + m * 16 + l15;
                    int pcol = (ks * 32 + l4 * 8) ^ ((prow & 7) << 3);
                    ap[m] = *(const bf16x8*)&Ps[prow * 64 + pcol];
                }
#pragma unroll
                for (int nd = 0; nd < 4; nd++) {
                    int vrow = nd * 16 + l15;
                    int vcol = (ks * 32 + l4 * 8) ^ ((vrow & 7) << 3);
                    bf16x8 bv = *(const bf16x8*)&Vl[vrow * 64 + vcol];
#pragma unroll
                    for (int m = 0; m < 4; m++)
                        o[m][nd] = mfma16(ap[m], bv, o[m][nd]);
                }
            }
            __builtin_amdgcn_s_setprio(0);
        }

        __syncthreads();
        cur ^= 1;
    }

    // final row-sum reduce across the 16-lane k-slices, normalize + store
#pragma unroll
    for (int d = 1; d < 16; d <<= 1)
#pragma unroll
        for (int m = 0; m < 4; m++)
#pragma unroll
            for (int r = 0; r < 4; r++) lr[m][r] += __shfl_xor(lr[m][r], d);

#pragma unroll
    for (int m = 0; m < 4; m++) {
        f32x4 inv;
#pragma unroll
        for (int r = 0; r < 4; r++) inv[r] = 1.0f / lr[m][r];
#pragma unroll
        for (int nd = 0; nd < 4; nd++)
#pragma unroll
            for (int r = 0; r < 4; r++) {
                int qrow = qt * 256 + wv * 64 + m * 16 + l4 * 4 + r;
                Attn[((size_t)(qrow * BSZ + b)) * DMODEL + h * 64 + nd * 16 + l15] =
                    (__bf16)(o[m][nd][r] * inv[r]);
            }
    }
}

// ---------------------------- launcher -------------------------------------
extern "C" void kernel_launch(void* const* d_in, const int* in_sizes, int n_in,
                              void* d_out, int out_size, void* d_ws, size_t ws_size,
                              hipStream_t stream) {
    const float* query  = (const float*)d_in[0];
    const float* keys   = (const float*)d_in[1];
    const float* values = (const float*)d_in[2];
    const int*   mask   = (const int*)d_in[3];
    const float* Wq     = (const float*)d_in[4];
    const float* Wk     = (const float*)d_in[5];
    const float* Wv     = (const float*)d_in[6];
    const float* Wo     = (const float*)d_in[7];
    float* out = (float*)d_out;

    char* ws = (char*)d_ws;
    const size_t MB = 1024 * 1024;
    __bf16* XQ   = (__bf16*)(ws + 0);
    __bf16* XK   = (__bf16*)(ws + 8 * MB);
    __bf16* XV   = (__bf16*)(ws + 16 * MB);
    __bf16* WCAT = (__bf16*)(ws + 24 * MB);   // [3072][1024]: Wq|Wk|Wv
    __bf16* WQB  = WCAT;
    __bf16* WKB  = (__bf16*)(ws + 26 * MB);
    __bf16* WVB  = (__bf16*)(ws + 28 * MB);
    __bf16* WOB  = (__bf16*)(ws + 30 * MB);
    __bf16* QKV  = (__bf16*)(ws + 32 * MB);   // [4096][3072] = 24 MB
    __bf16* VT   = (__bf16*)(ws + 0);         // reuse XQ (free after gemm_qkv)
    __bf16* ATT  = (__bf16*)(ws + 8 * MB);    // reuse XK
    unsigned int* flag = (unsigned int*)(ws + 56 * MB);

    (void)hipMemsetAsync(flag, 0xFF, 4, stream);

    const int NTOK = SLEN * BSZ;  // 4096
    const int NBIG = NTOK * DMODEL / 4, NW = DMODEL * DMODEL / 4;
    const float LOG2E = 1.4426950408889634f;
    CvtArgs ca;
    ca.src[0] = query;  ca.dst[0] = XQ;  ca.n4[0] = NBIG; ca.scale[0] = 1.0f;
    ca.src[1] = keys;   ca.dst[1] = XK;  ca.n4[1] = NBIG; ca.scale[1] = 1.0f;
    ca.src[2] = values; ca.dst[2] = XV;  ca.n4[2] = NBIG; ca.scale[2] = 1.0f;
    ca.src[3] = Wq;     ca.dst[3] = WQB; ca.n4[3] = NW;   ca.scale[3] = LOG2E;
    ca.src[4] = Wk;     ca.dst[4] = WKB; ca.n4[4] = NW;   ca.scale[4] = 1.0f;
    ca.src[5] = Wv;     ca.dst[5] = WVB; ca.n4[5] = NW;   ca.scale[5] = 1.0f;
    ca.src[6] = Wo;     ca.dst[6] = WOB; ca.n4[6] = NW;   ca.scale[6] = 1.0f;
    ca.mask = mask; ca.flag = flag; ca.maskn4 = SLEN * SLEN / 4;
    cvt_all<<<dim3(256, 8), 256, 0, stream>>>(ca);

    // fused QKV projection: grid (32, 48) = 1536 blocks (128x64 tiles)
    gemm_qkv<<<dim3(NTOK / 128, D3 / 64), 256, 0, stream>>>(XQ, XK, XV, WCAT, QKV);

    transpose_v<<<dim3(SLEN / 64, BSZ * NHEAD), 256, 0, stream>>>(QKV, VT);

    attn_fwd<<<BSZ * NHEAD * (SLEN / 256), 256, 0, stream>>>(QKV, VT, mask, flag, ATT);

    gemm_out<<<dim3(NTOK / 128, DMODEL / 64), 256, 0, stream>>>(ATT, WOB, out);
}

// Round 13
// 143.834 us; speedup vs baseline: 1.0452x; 1.0452x over previous
//
#include <hip/hip_runtime.h>

// ---------------------------------------------------------------------------
// MultiHeadAttention forward, MI355X (gfx950), bf16 MFMA pipeline. Round 13:
//  - attn: REVERT to R11 config (QBLK=128, KBLK=128 staged 2x64, 80KB LDS,
//    grid 512 = 2 blocks/CU, XCD swizzle). R12's QBLK=256 -> 1 blk/CU was
//    latency-bound (occ 10%, 78.6us). R11 measured 59.6us.
//  - cvt_all + mask flag fused (one dispatch).
//  - GEMMs: 128x64x64 dbuf + bijective XCD chunking on 1D grid (T1).
// ---------------------------------------------------------------------------

typedef __attribute__((ext_vector_type(4))) float  f32x4;
typedef __attribute__((ext_vector_type(8))) __bf16 bf16x8;
typedef __attribute__((ext_vector_type(4))) __bf16 bf16x4;

#define SLEN 2048
#define BSZ  2
#define DMODEL 1024
#define NHEAD 16
#define DHEAD 64
#define D3 (3 * DMODEL)   // 3072

__device__ __forceinline__ void async16(void* lds, const void* g) {
    __builtin_amdgcn_global_load_lds(
        (const __attribute__((address_space(1))) unsigned int*)g,
        (__attribute__((address_space(3))) unsigned int*)lds, 16, 0, 0);
}

__device__ __forceinline__ f32x4 mfma16(bf16x8 a, bf16x8 b, f32x4 c) {
    return __builtin_amdgcn_mfma_f32_16x16x32_bf16(a, b, c, 0, 0, 0);
}

// ------------------- fused convert fp32 -> bf16 (+ mask flag) --------------
struct CvtArgs {
    const float* src[7];
    __bf16* dst[7];
    int n4[7];
    float scale[7];
    const int* mask;
    unsigned int* flag;
    int maskn4;
};
__global__ void cvt_all(CvtArgs a) {
    const int t = blockIdx.y;
    const int stride = gridDim.x * blockDim.x;
    if (t == 7) {
        bool ok = true;
        for (int i = blockIdx.x * blockDim.x + threadIdx.x; i < a.maskn4; i += stride) {
            int4 v = ((const int4*)a.mask)[i];
            ok = ok && v.x && v.y && v.z && v.w;
        }
        if (!ok) atomicAnd(a.flag, 0u);
        return;
    }
    const float* __restrict__ src = a.src[t];
    __bf16* __restrict__ dst = a.dst[t];
    const int n4 = a.n4[t];
    const float sc = a.scale[t];
    for (int i = blockIdx.x * blockDim.x + threadIdx.x; i < n4; i += stride) {
        float4 v = ((const float4*)src)[i];
        bf16x4 o;
        o[0] = (__bf16)(v.x * sc); o[1] = (__bf16)(v.y * sc);
        o[2] = (__bf16)(v.z * sc); o[3] = (__bf16)(v.w * sc);
        ((bf16x4*)dst)[i] = o;
    }
}

// ---------------------------- GEMM core: 128x64x64 dbuf --------------------
template <typename CT>
__device__ __forceinline__ void gemm_core(const char* Ab, const char* Bb, int K,
                                          CT* Cv, size_t crow0, size_t ccol0,
                                          size_t ldc) {
    __shared__ __bf16 At[2][128 * 64];
    __shared__ __bf16 Bt[2][64 * 64];
    const int tid = threadIdx.x;
    const int lane = tid & 63, wv = tid >> 6;
    const int l15 = lane & 15, l4 = lane >> 4;
    const int wr = wv >> 1, wc = wv & 1;
    const int srow = lane >> 3;
    const int sbyte = (((lane & 7) ^ srow) << 4);

    f32x4 acc[4][2];
#pragma unroll
    for (int m = 0; m < 4; m++)
#pragma unroll
        for (int n = 0; n < 2; n++)
#pragma unroll
            for (int r = 0; r < 4; r++) acc[m][n][r] = 0.0f;

    auto stage = [&](int buf, int k0) {
#pragma unroll
        for (int i = 0; i < 6; i++) {
            int c = wv * 6 + i;
            if (c < 16) {
                int row = c * 8 + srow;
                async16(&At[buf][c * 512], Ab + ((size_t)row * K + k0) * 2 + sbyte);
            } else {
                int row = (c - 16) * 8 + srow;
                async16(&Bt[buf][(c - 16) * 512], Bb + ((size_t)row * K + k0) * 2 + sbyte);
            }
        }
    };

    stage(0, 0);
    __syncthreads();
    int cur = 0;
    for (int k0 = 0; k0 < K; k0 += 64) {
        if (k0 + 64 < K) stage(cur ^ 1, k0 + 64);
#pragma unroll
        for (int kk = 0; kk < 2; kk++) {
            bf16x8 af[4], bfr[2];
#pragma unroll
            for (int m = 0; m < 4; m++) {
                int row = wr * 64 + m * 16 + l15;
                int col = (kk * 32 + l4 * 8) ^ ((row & 7) << 3);
                af[m] = *(const bf16x8*)&At[cur][row * 64 + col];
            }
#pragma unroll
            for (int n = 0; n < 2; n++) {
                int row = wc * 32 + n * 16 + l15;
                int col = (kk * 32 + l4 * 8) ^ ((row & 7) << 3);
                bfr[n] = *(const bf16x8*)&Bt[cur][row * 64 + col];
            }
#pragma unroll
            for (int m = 0; m < 4; m++)
#pragma unroll
                for (int n = 0; n < 2; n++)
                    acc[m][n] = mfma16(af[m], bfr[n], acc[m][n]);
        }
        __syncthreads();
        cur ^= 1;
    }

#pragma unroll
    for (int m = 0; m < 4; m++)
#pragma unroll
        for (int n = 0; n < 2; n++)
#pragma unroll
            for (int r = 0; r < 4; r++) {
                size_t row = crow0 + wr * 64 + m * 16 + l4 * 4 + r;
                size_t col = ccol0 + wc * 32 + n * 16 + l15;
                Cv[row * ldc + col] = (CT)acc[m][n][r];
            }
}

// fused QKV projection: 1D grid 1536, XCD-chunked; tile (bm, bn) from swz id.
__global__ __launch_bounds__(256, 2) void gemm_qkv(const __bf16* __restrict__ Xq,
                                                   const __bf16* __restrict__ Xk,
                                                   const __bf16* __restrict__ Xv,
                                                   const __bf16* __restrict__ W,
                                                   __bf16* __restrict__ C) {
    // bijective XCD chunking: 1536 blocks, 8 XCDs, 192-block chunks
    const int i = blockIdx.x;
    const int swz = (i & 7) * 192 + (i >> 3);
    const int bn = swz / 32, bm = swz % 32;   // same-bn blocks contiguous
    const __bf16* A = (bn < 16) ? Xq : (bn < 32) ? Xk : Xv;
    gemm_core<__bf16>((const char*)(A + (size_t)bm * 128 * DMODEL),
                      (const char*)(W + (size_t)bn * 64 * DMODEL), DMODEL,
                      C, (size_t)bm * 128, (size_t)bn * 64, D3);
}

// out GEMM: 1D grid 512, XCD-chunked; fp32 out.
__global__ __launch_bounds__(256, 2) void gemm_out(const __bf16* __restrict__ A,
                                                   const __bf16* __restrict__ B,
                                                   float* __restrict__ Cv) {
    const int i = blockIdx.x;
    const int swz = (i & 7) * 64 + (i >> 3);
    const int bn = swz / 32, bm = swz % 32;
    gemm_core<float>((const char*)(A + (size_t)bm * 128 * DMODEL),
                     (const char*)(B + (size_t)bn * 64 * DMODEL), DMODEL,
                     Cv, (size_t)bm * 128, (size_t)bn * 64, DMODEL);
}

// ---------------------------- V transpose ----------------------------------
__global__ __launch_bounds__(256) void transpose_v(const __bf16* __restrict__ QKV,
                                                   __bf16* __restrict__ Vt) {
    __shared__ __bf16 t[64][72];
    const int stile = blockIdx.x;
    const int bh = blockIdx.y;
    const int b = bh >> 4, h = bh & 15;
    const int tid = threadIdx.x;
    {
        int sr = tid >> 2, d0 = (tid & 3) * 16;
        const __bf16* src = QKV + ((size_t)((stile * 64 + sr) * BSZ + b) * D3 + 2 * DMODEL + h * 64 + d0);
        *(bf16x8*)&t[sr][d0]     = *(const bf16x8*)src;
        *(bf16x8*)&t[sr][d0 + 8] = *(const bf16x8*)(src + 8);
    }
    __syncthreads();
    {
        int d = tid >> 2, s0 = (tid & 3) * 16;
        bf16x8 o1, o2;
#pragma unroll
        for (int j = 0; j < 8; j++) { o1[j] = t[s0 + j][d]; o2[j] = t[s0 + 8 + j][d]; }
        __bf16* dst = Vt + ((size_t)(bh * 64 + d) * SLEN + stile * 64 + s0);
        *(bf16x8*)dst = o1;
        *(bf16x8*)(dst + 8) = o2;
    }
}

// ---------------------------- attention (R11 config) -----------------------
// grid 512; XCD swizzle: blk&7 -> xcd, 4 bh x 16 qt per XCD.
// QBLK=128 (4 waves x 32 q), KBLK=128 staged (2x64 halves), dbuf, 80KB LDS.
__global__ __launch_bounds__(256, 2) void attn_fwd(const __bf16* __restrict__ QKV,
                                                   const __bf16* __restrict__ Vt,
                                                   const int* __restrict__ mask,
                                                   const unsigned int* __restrict__ flag,
                                                   __bf16* __restrict__ Attn) {
    __shared__ __bf16 Kt[2][2][64 * 64];   // [buf][kh][k][d]
    __shared__ __bf16 Vs[2][2][64 * 64];   // [buf][kh][d][k]
    __shared__ __bf16 Ps[128 * 64];        // [q][k64] (wave-private rows)
    const int tid = threadIdx.x;
    const int lane = tid & 63, wv = tid >> 6;
    const int l15 = lane & 15, l4 = lane >> 4;
    const int blk = blockIdx.x;
    const int xcd = blk & 7, idx = blk >> 3;
    const int bh = xcd + (idx >> 4) * 8;
    const int qt = idx & 15;
    const int b = bh >> 4, h = bh & 15;
    const bool allones = (*flag != 0u);
    const int srow = lane >> 3;
    const int sbyte = (((lane & 7) ^ srow) << 4);

    bf16x8 aq[2][2];
#pragma unroll
    for (int m = 0; m < 2; m++)
#pragma unroll
        for (int kk = 0; kk < 2; kk++) {
            int qrow = qt * 128 + wv * 32 + m * 16 + l15;
            aq[m][kk] = *(const bf16x8*)(QKV + ((size_t)(qrow * BSZ + b) * D3 + h * 64 + kk * 32 + l4 * 8));
        }

    f32x4 o[2][4], lr[2];
#pragma unroll
    for (int m = 0; m < 2; m++) {
#pragma unroll
        for (int nd = 0; nd < 4; nd++)
#pragma unroll
            for (int r = 0; r < 4; r++) o[m][nd][r] = 0.0f;
#pragma unroll
        for (int r = 0; r < 4; r++) lr[m][r] = 0.0f;
    }

    const char* Kb = (const char*)QKV + ((size_t)b * D3 + DMODEL + h * 64) * 2;
    const char* Vb = (const char*)Vt + ((size_t)bh * 64) * SLEN * 2;

    auto stage = [&](int buf, int kt) {
#pragma unroll
        for (int i = 0; i < 8; i++) {
            int c = wv * 8 + i;  // 0..31
            if (c < 16) {
                int kh = c >> 3, ck = c & 7;
                int krow = kt * 128 + kh * 64 + ck * 8 + srow;
                async16(&Kt[buf][kh][ck * 512],
                        Kb + (size_t)krow * (BSZ * D3 * 2) + sbyte);
            } else {
                int c2 = c - 16;
                int kh = c2 >> 3, ck = c2 & 7;
                int drow = ck * 8 + srow;
                async16(&Vs[buf][kh][ck * 512],
                        Vb + (size_t)drow * (SLEN * 2) + kt * 256 + kh * 128 + sbyte);
            }
        }
    };

    stage(0, 0);
    __syncthreads();
    int cur = 0;

    for (int kt = 0; kt < SLEN / 128; kt++) {
        if (kt + 1 < SLEN / 128) stage(cur ^ 1, kt + 1);

#pragma unroll
        for (int kh = 0; kh < 2; kh++) {
            const __bf16* Kl = Kt[cur][kh];
            const __bf16* Vl = Vs[cur][kh];

            f32x4 s[2][4];
#pragma unroll
            for (int m = 0; m < 2; m++)
#pragma unroll
                for (int n = 0; n < 4; n++)
#pragma unroll
                    for (int r = 0; r < 4; r++) s[m][n][r] = 0.0f;
            __builtin_amdgcn_s_setprio(1);
#pragma unroll
            for (int n = 0; n < 4; n++) {
                int row = n * 16 + l15;
#pragma unroll
                for (int kk = 0; kk < 2; kk++) {
                    int col = (kk * 32 + l4 * 8) ^ ((row & 7) << 3);
                    bf16x8 bk = *(const bf16x8*)&Kl[row * 64 + col];
#pragma unroll
                    for (int m = 0; m < 2; m++)
                        s[m][n] = mfma16(aq[m][kk], bk, s[m][n]);
                }
            }
            __builtin_amdgcn_s_setprio(0);

            if (!allones) {
#pragma unroll
                for (int m = 0; m < 2; m++)
#pragma unroll
                    for (int n = 0; n < 4; n++)
#pragma unroll
                        for (int r = 0; r < 4; r++) {
                            int q = qt * 128 + wv * 32 + m * 16 + l4 * 4 + r;
                            int kg = kt * 128 + kh * 64 + n * 16 + l15;
                            if (mask[(size_t)q * SLEN + kg] == 0) s[m][n][r] = -1e20f;
                        }
            }

#pragma unroll
            for (int m = 0; m < 2; m++)
#pragma unroll
                for (int n = 0; n < 4; n++)
#pragma unroll
                    for (int r = 0; r < 4; r++) {
                        float p = __builtin_amdgcn_exp2f(s[m][n][r]);
                        lr[m][r] += p;
                        int row = wv * 32 + m * 16 + l4 * 4 + r;
                        int col = (n * 16 + l15) ^ ((row & 7) << 3);
                        Ps[row * 64 + col] = (__bf16)p;
                    }

            __builtin_amdgcn_s_setprio(1);
#pragma unroll
            for (int ks = 0; ks < 2; ks++) {
                bf16x8 ap[2];
#pragma unroll
                for (int m = 0; m < 2; m++) {
                    int prow = wv * 32 + m * 16 + l15;
                    int pcol = (ks * 32 + l4 * 8) ^ ((prow & 7) << 3);
                    ap[m] = *(const bf16x8*)&Ps[prow * 64 + pcol];
                }
#pragma unroll
                for (int nd = 0; nd < 4; nd++) {
                    int vrow = nd * 16 + l15;
                    int vcol = (ks * 32 + l4 * 8) ^ ((vrow & 7) << 3);
                    bf16x8 bv = *(const bf16x8*)&Vl[vrow * 64 + vcol];
#pragma unroll
                    for (int m = 0; m < 2; m++)
                        o[m][nd] = mfma16(ap[m], bv, o[m][nd]);
                }
            }
            __builtin_amdgcn_s_setprio(0);
        }

        __syncthreads();
        cur ^= 1;
    }

#pragma unroll
    for (int d = 1; d < 16; d <<= 1)
#pragma unroll
        for (int m = 0; m < 2; m++)
#pragma unroll
            for (int r = 0; r < 4; r++) lr[m][r] += __shfl_xor(lr[m][r], d);

#pragma unroll
    for (int m = 0; m < 2; m++) {
        f32x4 inv;
#pragma unroll
        for (int r = 0; r < 4; r++) inv[r] = 1.0f / lr[m][r];
#pragma unroll
        for (int nd = 0; nd < 4; nd++)
#pragma unroll
            for (int r = 0; r < 4; r++) {
                int qrow = qt * 128 + wv * 32 + m * 16 + l4 * 4 + r;
                Attn[((size_t)(qrow * BSZ + b)) * DMODEL + h * 64 + nd * 16 + l15] =
                    (__bf16)(o[m][nd][r] * inv[r]);
            }
    }
}

// ---------------------------- launcher -------------------------------------
extern "C" void kernel_launch(void* const* d_in, const int* in_sizes, int n_in,
                              void* d_out, int out_size, void* d_ws, size_t ws_size,
                              hipStream_t stream) {
    const float* query  = (const float*)d_in[0];
    const float* keys   = (const float*)d_in[1];
    const float* values = (const float*)d_in[2];
    const int*   mask   = (const int*)d_in[3];
    const float* Wq     = (const float*)d_in[4];
    const float* Wk     = (const float*)d_in[5];
    const float* Wv     = (const float*)d_in[6];
    const float* Wo     = (const float*)d_in[7];
    float* out = (float*)d_out;

    char* ws = (char*)d_ws;
    const size_t MB = 1024 * 1024;
    __bf16* XQ   = (__bf16*)(ws + 0);
    __bf16* XK   = (__bf16*)(ws + 8 * MB);
    __bf16* XV   = (__bf16*)(ws + 16 * MB);
    __bf16* WCAT = (__bf16*)(ws + 24 * MB);   // [3072][1024]: Wq|Wk|Wv
    __bf16* WQB  = WCAT;
    __bf16* WKB  = (__bf16*)(ws + 26 * MB);
    __bf16* WVB  = (__bf16*)(ws + 28 * MB);
    __bf16* WOB  = (__bf16*)(ws + 30 * MB);
    __bf16* QKV  = (__bf16*)(ws + 32 * MB);   // [4096][3072] = 24 MB
    __bf16* VT   = (__bf16*)(ws + 0);         // reuse XQ (free after gemm_qkv)
    __bf16* ATT  = (__bf16*)(ws + 8 * MB);    // reuse XK
    unsigned int* flag = (unsigned int*)(ws + 56 * MB);

    (void)hipMemsetAsync(flag, 0xFF, 4, stream);

    const int NTOK = SLEN * BSZ;  // 4096
    const int NBIG = NTOK * DMODEL / 4, NW = DMODEL * DMODEL / 4;
    const float LOG2E = 1.4426950408889634f;
    CvtArgs ca;
    ca.src[0] = query;  ca.dst[0] = XQ;  ca.n4[0] = NBIG; ca.scale[0] = 1.0f;
    ca.src[1] = keys;   ca.dst[1] = XK;  ca.n4[1] = NBIG; ca.scale[1] = 1.0f;
    ca.src[2] = values; ca.dst[2] = XV;  ca.n4[2] = NBIG; ca.scale[2] = 1.0f;
    ca.src[3] = Wq;     ca.dst[3] = WQB; ca.n4[3] = NW;   ca.scale[3] = LOG2E;
    ca.src[4] = Wk;     ca.dst[4] = WKB; ca.n4[4] = NW;   ca.scale[4] = 1.0f;
    ca.src[5] = Wv;     ca.dst[5] = WVB; ca.n4[5] = NW;   ca.scale[5] = 1.0f;
    ca.src[6] = Wo;     ca.dst[6] = WOB; ca.n4[6] = NW;   ca.scale[6] = 1.0f;
    ca.mask = mask; ca.flag = flag; ca.maskn4 = SLEN * SLEN / 4;
    cvt_all<<<dim3(256, 8), 256, 0, stream>>>(ca);

    // fused QKV projection: 1536 blocks, XCD-chunked 1D grid
    gemm_qkv<<<1536, 256, 0, stream>>>(XQ, XK, XV, WCAT, QKV);

    transpose_v<<<dim3(SLEN / 64, BSZ * NHEAD), 256, 0, stream>>>(QKV, VT);

    attn_fwd<<<BSZ * NHEAD * (SLEN / 128), 256, 0, stream>>>(QKV, VT, mask, flag, ATT);

    gemm_out<<<512, 256, 0, stream>>>(ATT, WOB, out);
}

// Round 14
// 135.785 us; speedup vs baseline: 1.1071x; 1.0593x over previous
//
#include <hip/hip_runtime.h>

// ---------------------------------------------------------------------------
// MultiHeadAttention forward, MI355X (gfx950), bf16 MFMA pipeline. Round 14:
//  - GEMMs: revert to R11 2D grids (R13 XCD chunking hurt A-locality: each
//    XCD streamed a full 8MB A > 4MB L2).
//  - attn: swapped QK^T (S^T = mfma(K,Q)) -> P lives in registers; PV uses
//    mfma_f32_16x16x16_bf16 whose B-layout matches S^T's C-layout exactly.
//    Ps LDS buffer deleted (80->64 KB), no P writes/reads, O^T stores 8B.
//  - exp2-direct softmax (Wq pre-scaled log2e), cvt+mask fused, XCD swizzle.
// ---------------------------------------------------------------------------

typedef __attribute__((ext_vector_type(4))) float  f32x4;
typedef __attribute__((ext_vector_type(8))) __bf16 bf16x8;
typedef __attribute__((ext_vector_type(4))) __bf16 bf16x4;
typedef __attribute__((ext_vector_type(4))) short  s16x4;

#define SLEN 2048
#define BSZ  2
#define DMODEL 1024
#define NHEAD 16
#define DHEAD 64
#define D3 (3 * DMODEL)   // 3072

__device__ __forceinline__ void async16(void* lds, const void* g) {
    __builtin_amdgcn_global_load_lds(
        (const __attribute__((address_space(1))) unsigned int*)g,
        (__attribute__((address_space(3))) unsigned int*)lds, 16, 0, 0);
}

__device__ __forceinline__ f32x4 mfma16(bf16x8 a, bf16x8 b, f32x4 c) {
    return __builtin_amdgcn_mfma_f32_16x16x32_bf16(a, b, c, 0, 0, 0);
}

// K=16 variant: A/B = 4 bf16 (2 VGPR). Name differs across ROCm versions.
__device__ __forceinline__ f32x4 mfma16k16(bf16x4 a, bf16x4 b, f32x4 c) {
#if __has_builtin(__builtin_amdgcn_mfma_f32_16x16x16_bf16)
    return __builtin_amdgcn_mfma_f32_16x16x16_bf16(a, b, c, 0, 0, 0);
#else
    return __builtin_amdgcn_mfma_f32_16x16x16bf16_1k(
        __builtin_bit_cast(s16x4, a), __builtin_bit_cast(s16x4, b), c, 0, 0, 0);
#endif
}

// ------------------- fused convert fp32 -> bf16 (+ mask flag) --------------
struct CvtArgs {
    const float* src[7];
    __bf16* dst[7];
    int n4[7];
    float scale[7];
    const int* mask;
    unsigned int* flag;
    int maskn4;
};
__global__ void cvt_all(CvtArgs a) {
    const int t = blockIdx.y;
    const int stride = gridDim.x * blockDim.x;
    if (t == 7) {
        bool ok = true;
        for (int i = blockIdx.x * blockDim.x + threadIdx.x; i < a.maskn4; i += stride) {
            int4 v = ((const int4*)a.mask)[i];
            ok = ok && v.x && v.y && v.z && v.w;
        }
        if (!ok) atomicAnd(a.flag, 0u);
        return;
    }
    const float* __restrict__ src = a.src[t];
    __bf16* __restrict__ dst = a.dst[t];
    const int n4 = a.n4[t];
    const float sc = a.scale[t];
    for (int i = blockIdx.x * blockDim.x + threadIdx.x; i < n4; i += stride) {
        float4 v = ((const float4*)src)[i];
        bf16x4 o;
        o[0] = (__bf16)(v.x * sc); o[1] = (__bf16)(v.y * sc);
        o[2] = (__bf16)(v.z * sc); o[3] = (__bf16)(v.w * sc);
        ((bf16x4*)dst)[i] = o;
    }
}

// ---------------------------- GEMM core: 128x64x64 dbuf --------------------
template <typename CT>
__device__ __forceinline__ void gemm_core(const char* Ab, const char* Bb, int K,
                                          CT* Cv, size_t crow0, size_t ccol0,
                                          size_t ldc) {
    __shared__ __bf16 At[2][128 * 64];
    __shared__ __bf16 Bt[2][64 * 64];
    const int tid = threadIdx.x;
    const int lane = tid & 63, wv = tid >> 6;
    const int l15 = lane & 15, l4 = lane >> 4;
    const int wr = wv >> 1, wc = wv & 1;
    const int srow = lane >> 3;
    const int sbyte = (((lane & 7) ^ srow) << 4);

    f32x4 acc[4][2];
#pragma unroll
    for (int m = 0; m < 4; m++)
#pragma unroll
        for (int n = 0; n < 2; n++)
#pragma unroll
            for (int r = 0; r < 4; r++) acc[m][n][r] = 0.0f;

    auto stage = [&](int buf, int k0) {
#pragma unroll
        for (int i = 0; i < 6; i++) {
            int c = wv * 6 + i;
            if (c < 16) {
                int row = c * 8 + srow;
                async16(&At[buf][c * 512], Ab + ((size_t)row * K + k0) * 2 + sbyte);
            } else {
                int row = (c - 16) * 8 + srow;
                async16(&Bt[buf][(c - 16) * 512], Bb + ((size_t)row * K + k0) * 2 + sbyte);
            }
        }
    };

    stage(0, 0);
    __syncthreads();
    int cur = 0;
    for (int k0 = 0; k0 < K; k0 += 64) {
        if (k0 + 64 < K) stage(cur ^ 1, k0 + 64);
#pragma unroll
        for (int kk = 0; kk < 2; kk++) {
            bf16x8 af[4], bfr[2];
#pragma unroll
            for (int m = 0; m < 4; m++) {
                int row = wr * 64 + m * 16 + l15;
                int col = (kk * 32 + l4 * 8) ^ ((row & 7) << 3);
                af[m] = *(const bf16x8*)&At[cur][row * 64 + col];
            }
#pragma unroll
            for (int n = 0; n < 2; n++) {
                int row = wc * 32 + n * 16 + l15;
                int col = (kk * 32 + l4 * 8) ^ ((row & 7) << 3);
                bfr[n] = *(const bf16x8*)&Bt[cur][row * 64 + col];
            }
#pragma unroll
            for (int m = 0; m < 4; m++)
#pragma unroll
                for (int n = 0; n < 2; n++)
                    acc[m][n] = mfma16(af[m], bfr[n], acc[m][n]);
        }
        __syncthreads();
        cur ^= 1;
    }

#pragma unroll
    for (int m = 0; m < 4; m++)
#pragma unroll
        for (int n = 0; n < 2; n++)
#pragma unroll
            for (int r = 0; r < 4; r++) {
                size_t row = crow0 + wr * 64 + m * 16 + l4 * 4 + r;
                size_t col = ccol0 + wc * 32 + n * 16 + l15;
                Cv[row * ldc + col] = (CT)acc[m][n][r];
            }
}

// fused QKV projection: C[4096][3072] = A_sel @ W[3072][1024]^T, bn 0..47
__global__ __launch_bounds__(256, 2) void gemm_qkv(const __bf16* __restrict__ Xq,
                                                   const __bf16* __restrict__ Xk,
                                                   const __bf16* __restrict__ Xv,
                                                   const __bf16* __restrict__ W,
                                                   __bf16* __restrict__ C) {
    const int bm = blockIdx.x, bn = blockIdx.y;
    const __bf16* A = (bn < 16) ? Xq : (bn < 32) ? Xk : Xv;
    gemm_core<__bf16>((const char*)(A + (size_t)bm * 128 * DMODEL),
                      (const char*)(W + (size_t)bn * 64 * DMODEL), DMODEL,
                      C, (size_t)bm * 128, (size_t)bn * 64, D3);
}

// out GEMM: out[4096][1024] = ATT @ Wo^T, fp32 out, bn 0..15
__global__ __launch_bounds__(256, 2) void gemm_out(const __bf16* __restrict__ A,
                                                   const __bf16* __restrict__ B,
                                                   float* __restrict__ Cv) {
    const int bm = blockIdx.x, bn = blockIdx.y;
    gemm_core<float>((const char*)(A + (size_t)bm * 128 * DMODEL),
                     (const char*)(B + (size_t)bn * 64 * DMODEL), DMODEL,
                     Cv, (size_t)bm * 128, (size_t)bn * 64, DMODEL);
}

// ---------------------------- V transpose ----------------------------------
__global__ __launch_bounds__(256) void transpose_v(const __bf16* __restrict__ QKV,
                                                   __bf16* __restrict__ Vt) {
    __shared__ __bf16 t[64][72];
    const int stile = blockIdx.x;
    const int bh = blockIdx.y;
    const int b = bh >> 4, h = bh & 15;
    const int tid = threadIdx.x;
    {
        int sr = tid >> 2, d0 = (tid & 3) * 16;
        const __bf16* src = QKV + ((size_t)((stile * 64 + sr) * BSZ + b) * D3 + 2 * DMODEL + h * 64 + d0);
        *(bf16x8*)&t[sr][d0]     = *(const bf16x8*)src;
        *(bf16x8*)&t[sr][d0 + 8] = *(const bf16x8*)(src + 8);
    }
    __syncthreads();
    {
        int d = tid >> 2, s0 = (tid & 3) * 16;
        bf16x8 o1, o2;
#pragma unroll
        for (int j = 0; j < 8; j++) { o1[j] = t[s0 + j][d]; o2[j] = t[s0 + 8 + j][d]; }
        __bf16* dst = Vt + ((size_t)(bh * 64 + d) * SLEN + stile * 64 + s0);
        *(bf16x8*)dst = o1;
        *(bf16x8*)(dst + 8) = o2;
    }
}

// ---------------------------- attention (swapped QK^T) ---------------------
// grid 512; XCD swizzle. QBLK=128 (4 waves x 32 q), KBLK=128 (2x64 halves).
// S^T = mfma(K,Q): lane l15 = q, l4*4+r = k. P stays in registers; PV uses
// K=16 mfma whose B-layout == S^T C-layout. O^T: col=q=l15, row=d -> 8B store.
__global__ __launch_bounds__(256, 2) void attn_fwd(const __bf16* __restrict__ QKV,
                                                   const __bf16* __restrict__ Vt,
                                                   const int* __restrict__ mask,
                                                   const unsigned int* __restrict__ flag,
                                                   __bf16* __restrict__ Attn) {
    __shared__ __bf16 Kt[2][2][64 * 64];   // [buf][kh][k][d]  32 KB
    __shared__ __bf16 Vs[2][2][64 * 64];   // [buf][kh][d][k]  32 KB
    const int tid = threadIdx.x;
    const int lane = tid & 63, wv = tid >> 6;
    const int l15 = lane & 15, l4 = lane >> 4;
    const int blk = blockIdx.x;
    const int xcd = blk & 7, idx = blk >> 3;
    const int bh = xcd + (idx >> 4) * 8;
    const int qt = idx & 15;
    const int b = bh >> 4, h = bh & 15;
    const bool allones = (*flag != 0u);
    const int srow = lane >> 3;
    const int sbyte = (((lane & 7) ^ srow) << 4);

    // Q fragments (per wave: 32 q-rows x 64 d), used as the B-operand of QK^T
    bf16x8 aq[2][2];
#pragma unroll
    for (int m = 0; m < 2; m++)
#pragma unroll
        for (int kk = 0; kk < 2; kk++) {
            int qrow = qt * 128 + wv * 32 + m * 16 + l15;
            aq[m][kk] = *(const bf16x8*)(QKV + ((size_t)(qrow * BSZ + b) * D3 + h * 64 + kk * 32 + l4 * 8));
        }

    // O^T accumulators: o[m][nd]: col=q(l15, m-tile), row=d(l4*4+r, nd-tile)
    f32x4 o[2][4];
    float lr[2];
#pragma unroll
    for (int m = 0; m < 2; m++) {
#pragma unroll
        for (int nd = 0; nd < 4; nd++)
#pragma unroll
            for (int r = 0; r < 4; r++) o[m][nd][r] = 0.0f;
        lr[m] = 0.0f;
    }

    const char* Kb = (const char*)QKV + ((size_t)b * D3 + DMODEL + h * 64) * 2;
    const char* Vb = (const char*)Vt + ((size_t)bh * 64) * SLEN * 2;

    auto stage = [&](int buf, int kt) {
#pragma unroll
        for (int i = 0; i < 8; i++) {
            int c = wv * 8 + i;  // 0..31
            if (c < 16) {
                int kh = c >> 3, ck = c & 7;
                int krow = kt * 128 + kh * 64 + ck * 8 + srow;
                async16(&Kt[buf][kh][ck * 512],
                        Kb + (size_t)krow * (BSZ * D3 * 2) + sbyte);
            } else {
                int c2 = c - 16;
                int kh = c2 >> 3, ck = c2 & 7;
                int drow = ck * 8 + srow;
                async16(&Vs[buf][kh][ck * 512],
                        Vb + (size_t)drow * (SLEN * 2) + kt * 256 + kh * 128 + sbyte);
            }
        }
    };

    stage(0, 0);
    __syncthreads();
    int cur = 0;

    for (int kt = 0; kt < SLEN / 128; kt++) {
        if (kt + 1 < SLEN / 128) stage(cur ^ 1, kt + 1);

#pragma unroll
        for (int kh = 0; kh < 2; kh++) {
            const __bf16* Kl = Kt[cur][kh];
            const __bf16* Vl = Vs[cur][kh];

            // K fragments (A-operand): rows k = n*16+l15, d = kk*32+l4*8
            bf16x8 bk[4][2];
#pragma unroll
            for (int n = 0; n < 4; n++) {
                int row = n * 16 + l15;
#pragma unroll
                for (int kk = 0; kk < 2; kk++) {
                    int col = (kk * 32 + l4 * 8) ^ ((row & 7) << 3);
                    bk[n][kk] = *(const bf16x8*)&Kl[row * 64 + col];
                }
            }

            // S^T = K Q^T: s[m][n]: col=q(l15), row=k(n*16+l4*4+r)
            f32x4 s[2][4];
#pragma unroll
            for (int m = 0; m < 2; m++)
#pragma unroll
                for (int n = 0; n < 4; n++)
#pragma unroll
                    for (int r = 0; r < 4; r++) s[m][n][r] = 0.0f;
            __builtin_amdgcn_s_setprio(1);
#pragma unroll
            for (int n = 0; n < 4; n++)
#pragma unroll
                for (int kk = 0; kk < 2; kk++)
#pragma unroll
                    for (int m = 0; m < 2; m++)
                        s[m][n] = mfma16(bk[n][kk], aq[m][kk], s[m][n]);
            __builtin_amdgcn_s_setprio(0);

            if (!allones) {
#pragma unroll
                for (int m = 0; m < 2; m++) {
                    int q = qt * 128 + wv * 32 + m * 16 + l15;
#pragma unroll
                    for (int n = 0; n < 4; n++)
#pragma unroll
                        for (int r = 0; r < 4; r++) {
                            int kg = kt * 128 + kh * 64 + n * 16 + l4 * 4 + r;
                            if (mask[(size_t)q * SLEN + kg] == 0) s[m][n][r] = -1e20f;
                        }
                }
            }

            // exp2 (log2e folded into Wq), pack P^T fragments in-register
            bf16x4 pb[2][4];
#pragma unroll
            for (int m = 0; m < 2; m++)
#pragma unroll
                for (int n = 0; n < 4; n++) {
                    float p0 = __builtin_amdgcn_exp2f(s[m][n][0]);
                    float p1 = __builtin_amdgcn_exp2f(s[m][n][1]);
                    float p2 = __builtin_amdgcn_exp2f(s[m][n][2]);
                    float p3 = __builtin_amdgcn_exp2f(s[m][n][3]);
                    lr[m] += (p0 + p1) + (p2 + p3);
                    bf16x4 w;
                    w[0] = (__bf16)p0; w[1] = (__bf16)p1;
                    w[2] = (__bf16)p2; w[3] = (__bf16)p3;
                    pb[m][n] = w;
                }

            // V^T fragments (A-operand, K=16): row d = nd*16+l15, k = n*16+l4*4
            bf16x4 av[4][4];
#pragma unroll
            for (int nd = 0; nd < 4; nd++) {
                int row = nd * 16 + l15;
#pragma unroll
                for (int n = 0; n < 4; n++) {
                    int col = (n * 16 + l4 * 4) ^ ((row & 7) << 3);
                    av[nd][n] = *(const bf16x4*)&Vl[row * 64 + col];
                }
            }

            // O^T += V^T P^T  (K=16 mfma; B-operand = pb own-lane, no LDS)
            __builtin_amdgcn_s_setprio(1);
#pragma unroll
            for (int n = 0; n < 4; n++)
#pragma unroll
                for (int nd = 0; nd < 4; nd++)
#pragma unroll
                    for (int m = 0; m < 2; m++)
                        o[m][nd] = mfma16k16(av[nd][n], pb[m][n], o[m][nd]);
            __builtin_amdgcn_s_setprio(0);
        }

        __syncthreads();
        cur ^= 1;
    }

    // row-sum: lane has partial for q=l15; reduce across l4 groups
#pragma unroll
    for (int m = 0; m < 2; m++) {
        lr[m] += __shfl_xor(lr[m], 16);
        lr[m] += __shfl_xor(lr[m], 32);
    }

    // normalize + store O^T: per (m, nd): q = l15-based, d = l4*4+r (8B store)
#pragma unroll
    for (int m = 0; m < 2; m++) {
        float inv = 1.0f / lr[m];
        int qrow = qt * 128 + wv * 32 + m * 16 + l15;
#pragma unroll
        for (int nd = 0; nd < 4; nd++) {
            bf16x4 ov;
#pragma unroll
            for (int r = 0; r < 4; r++) ov[r] = (__bf16)(o[m][nd][r] * inv);
            *(bf16x4*)(Attn + ((size_t)(qrow * BSZ + b)) * DMODEL + h * 64 + nd * 16 + l4 * 4) = ov;
        }
    }
}

// ---------------------------- launcher -------------------------------------
extern "C" void kernel_launch(void* const* d_in, const int* in_sizes, int n_in,
                              void* d_out, int out_size, void* d_ws, size_t ws_size,
                              hipStream_t stream) {
    const float* query  = (const float*)d_in[0];
    const float* keys   = (const float*)d_in[1];
    const float* values = (const float*)d_in[2];
    const int*   mask   = (const int*)d_in[3];
    const float* Wq     = (const float*)d_in[4];
    const float* Wk     = (const float*)d_in[5];
    const float* Wv     = (const float*)d_in[6];
    const float* Wo     = (const float*)d_in[7];
    float* out = (float*)d_out;

    char* ws = (char*)d_ws;
    const size_t MB = 1024 * 1024;
    __bf16* XQ   = (__bf16*)(ws + 0);
    __bf16* XK   = (__bf16*)(ws + 8 * MB);
    __bf16* XV   = (__bf16*)(ws + 16 * MB);
    __bf16* WCAT = (__bf16*)(ws + 24 * MB);   // [3072][1024]: Wq|Wk|Wv
    __bf16* WQB  = WCAT;
    __bf16* WKB  = (__bf16*)(ws + 26 * MB);
    __bf16* WVB  = (__bf16*)(ws + 28 * MB);
    __bf16* WOB  = (__bf16*)(ws + 30 * MB);
    __bf16* QKV  = (__bf16*)(ws + 32 * MB);   // [4096][3072] = 24 MB
    __bf16* VT   = (__bf16*)(ws + 0);         // reuse XQ (free after gemm_qkv)
    __bf16* ATT  = (__bf16*)(ws + 8 * MB);    // reuse XK
    unsigned int* flag = (unsigned int*)(ws + 56 * MB);

    (void)hipMemsetAsync(flag, 0xFF, 4, stream);

    const int NTOK = SLEN * BSZ;  // 4096
    const int NBIG = NTOK * DMODEL / 4, NW = DMODEL * DMODEL / 4;
    const float LOG2E = 1.4426950408889634f;
    CvtArgs ca;
    ca.src[0] = query;  ca.dst[0] = XQ;  ca.n4[0] = NBIG; ca.scale[0] = 1.0f;
    ca.src[1] = keys;   ca.dst[1] = XK;  ca.n4[1] = NBIG; ca.scale[1] = 1.0f;
    ca.src[2] = values; ca.dst[2] = XV;  ca.n4[2] = NBIG; ca.scale[2] = 1.0f;
    ca.src[3] = Wq;     ca.dst[3] = WQB; ca.n4[3] = NW;   ca.scale[3] = LOG2E;
    ca.src[4] = Wk;     ca.dst[4] = WKB; ca.n4[4] = NW;   ca.scale[4] = 1.0f;
    ca.src[5] = Wv;     ca.dst[5] = WVB; ca.n4[5] = NW;   ca.scale[5] = 1.0f;
    ca.src[6] = Wo;     ca.dst[6] = WOB; ca.n4[6] = NW;   ca.scale[6] = 1.0f;
    ca.mask = mask; ca.flag = flag; ca.maskn4 = SLEN * SLEN / 4;
    cvt_all<<<dim3(256, 8), 256, 0, stream>>>(ca);

    // fused QKV projection: grid (32, 48) = 1536 blocks (128x64 tiles)
    gemm_qkv<<<dim3(NTOK / 128, D3 / 64), 256, 0, stream>>>(XQ, XK, XV, WCAT, QKV);

    transpose_v<<<dim3(SLEN / 64, BSZ * NHEAD), 256, 0, stream>>>(QKV, VT);

    attn_fwd<<<BSZ * NHEAD * (SLEN / 128), 256, 0, stream>>>(QKV, VT, mask, flag, ATT);

    gemm_out<<<dim3(NTOK / 128, DMODEL / 64), 256, 0, stream>>>(ATT, WOB, out);
}

// Round 15
// 135.271 us; speedup vs baseline: 1.1113x; 1.0038x over previous
//
#include <hip/hip_runtime.h>

// ---------------------------------------------------------------------------
// MultiHeadAttention forward, MI355X (gfx950), bf16 MFMA pipeline. Round 15:
//  - attn: R14 swapped-QK^T structure, but VT k-order permuted per 64-block
//    (k' = l4*16 + n*4 + r) so the four K=16 V^T fragments per lane are one
//    contiguous 32B span -> av = 2x b128 swizzled reads (was 16x b64, 4-way
//    bank conflict, 4.19M/dispatch in R14).
//  - GEMMs: R11 128x64x64 dbuf 2D grids. cvt+mask fused. XCD swizzle.
// ---------------------------------------------------------------------------

typedef __attribute__((ext_vector_type(4))) float  f32x4;
typedef __attribute__((ext_vector_type(8))) __bf16 bf16x8;
typedef __attribute__((ext_vector_type(4))) __bf16 bf16x4;
typedef __attribute__((ext_vector_type(4))) short  s16x4;

#define SLEN 2048
#define BSZ  2
#define DMODEL 1024
#define NHEAD 16
#define DHEAD 64
#define D3 (3 * DMODEL)   // 3072

__device__ __forceinline__ void async16(void* lds, const void* g) {
    __builtin_amdgcn_global_load_lds(
        (const __attribute__((address_space(1))) unsigned int*)g,
        (__attribute__((address_space(3))) unsigned int*)lds, 16, 0, 0);
}

__device__ __forceinline__ f32x4 mfma16(bf16x8 a, bf16x8 b, f32x4 c) {
    return __builtin_amdgcn_mfma_f32_16x16x32_bf16(a, b, c, 0, 0, 0);
}

// K=16 variant: A/B = 4 bf16 (2 VGPR).
__device__ __forceinline__ f32x4 mfma16k16(bf16x4 a, bf16x4 b, f32x4 c) {
#if __has_builtin(__builtin_amdgcn_mfma_f32_16x16x16_bf16)
    return __builtin_amdgcn_mfma_f32_16x16x16_bf16(a, b, c, 0, 0, 0);
#else
    return __builtin_amdgcn_mfma_f32_16x16x16bf16_1k(
        __builtin_bit_cast(s16x4, a), __builtin_bit_cast(s16x4, b), c, 0, 0, 0);
#endif
}

// ------------------- fused convert fp32 -> bf16 (+ mask flag) --------------
struct CvtArgs {
    const float* src[7];
    __bf16* dst[7];
    int n4[7];
    float scale[7];
    const int* mask;
    unsigned int* flag;
    int maskn4;
};
__global__ void cvt_all(CvtArgs a) {
    const int t = blockIdx.y;
    const int stride = gridDim.x * blockDim.x;
    if (t == 7) {
        bool ok = true;
        for (int i = blockIdx.x * blockDim.x + threadIdx.x; i < a.maskn4; i += stride) {
            int4 v = ((const int4*)a.mask)[i];
            ok = ok && v.x && v.y && v.z && v.w;
        }
        if (!ok) atomicAnd(a.flag, 0u);
        return;
    }
    const float* __restrict__ src = a.src[t];
    __bf16* __restrict__ dst = a.dst[t];
    const int n4 = a.n4[t];
    const float sc = a.scale[t];
    for (int i = blockIdx.x * blockDim.x + threadIdx.x; i < n4; i += stride) {
        float4 v = ((const float4*)src)[i];
        bf16x4 o;
        o[0] = (__bf16)(v.x * sc); o[1] = (__bf16)(v.y * sc);
        o[2] = (__bf16)(v.z * sc); o[3] = (__bf16)(v.w * sc);
        ((bf16x4*)dst)[i] = o;
    }
}

// ---------------------------- GEMM core: 128x64x64 dbuf --------------------
template <typename CT>
__device__ __forceinline__ void gemm_core(const char* Ab, const char* Bb, int K,
                                          CT* Cv, size_t crow0, size_t ccol0,
                                          size_t ldc) {
    __shared__ __bf16 At[2][128 * 64];
    __shared__ __bf16 Bt[2][64 * 64];
    const int tid = threadIdx.x;
    const int lane = tid & 63, wv = tid >> 6;
    const int l15 = lane & 15, l4 = lane >> 4;
    const int wr = wv >> 1, wc = wv & 1;
    const int srow = lane >> 3;
    const int sbyte = (((lane & 7) ^ srow) << 4);

    f32x4 acc[4][2];
#pragma unroll
    for (int m = 0; m < 4; m++)
#pragma unroll
        for (int n = 0; n < 2; n++)
#pragma unroll
            for (int r = 0; r < 4; r++) acc[m][n][r] = 0.0f;

    auto stage = [&](int buf, int k0) {
#pragma unroll
        for (int i = 0; i < 6; i++) {
            int c = wv * 6 + i;
            if (c < 16) {
                int row = c * 8 + srow;
                async16(&At[buf][c * 512], Ab + ((size_t)row * K + k0) * 2 + sbyte);
            } else {
                int row = (c - 16) * 8 + srow;
                async16(&Bt[buf][(c - 16) * 512], Bb + ((size_t)row * K + k0) * 2 + sbyte);
            }
        }
    };

    stage(0, 0);
    __syncthreads();
    int cur = 0;
    for (int k0 = 0; k0 < K; k0 += 64) {
        if (k0 + 64 < K) stage(cur ^ 1, k0 + 64);
#pragma unroll
        for (int kk = 0; kk < 2; kk++) {
            bf16x8 af[4], bfr[2];
#pragma unroll
            for (int m = 0; m < 4; m++) {
                int row = wr * 64 + m * 16 + l15;
                int col = (kk * 32 + l4 * 8) ^ ((row & 7) << 3);
                af[m] = *(const bf16x8*)&At[cur][row * 64 + col];
            }
#pragma unroll
            for (int n = 0; n < 2; n++) {
                int row = wc * 32 + n * 16 + l15;
                int col = (kk * 32 + l4 * 8) ^ ((row & 7) << 3);
                bfr[n] = *(const bf16x8*)&Bt[cur][row * 64 + col];
            }
#pragma unroll
            for (int m = 0; m < 4; m++)
#pragma unroll
                for (int n = 0; n < 2; n++)
                    acc[m][n] = mfma16(af[m], bfr[n], acc[m][n]);
        }
        __syncthreads();
        cur ^= 1;
    }

#pragma unroll
    for (int m = 0; m < 4; m++)
#pragma unroll
        for (int n = 0; n < 2; n++)
#pragma unroll
            for (int r = 0; r < 4; r++) {
                size_t row = crow0 + wr * 64 + m * 16 + l4 * 4 + r;
                size_t col = ccol0 + wc * 32 + n * 16 + l15;
                Cv[row * ldc + col] = (CT)acc[m][n][r];
            }
}

// fused QKV projection: C[4096][3072] = A_sel @ W[3072][1024]^T, bn 0..47
__global__ __launch_bounds__(256, 2) void gemm_qkv(const __bf16* __restrict__ Xq,
                                                   const __bf16* __restrict__ Xk,
                                                   const __bf16* __restrict__ Xv,
                                                   const __bf16* __restrict__ W,
                                                   __bf16* __restrict__ C) {
    const int bm = blockIdx.x, bn = blockIdx.y;
    const __bf16* A = (bn < 16) ? Xq : (bn < 32) ? Xk : Xv;
    gemm_core<__bf16>((const char*)(A + (size_t)bm * 128 * DMODEL),
                      (const char*)(W + (size_t)bn * 64 * DMODEL), DMODEL,
                      C, (size_t)bm * 128, (size_t)bn * 64, D3);
}

// out GEMM: out[4096][1024] = ATT @ Wo^T, fp32 out, bn 0..15
__global__ __launch_bounds__(256, 2) void gemm_out(const __bf16* __restrict__ A,
                                                   const __bf16* __restrict__ B,
                                                   float* __restrict__ Cv) {
    const int bm = blockIdx.x, bn = blockIdx.y;
    gemm_core<float>((const char*)(A + (size_t)bm * 128 * DMODEL),
                     (const char*)(B + (size_t)bn * 64 * DMODEL), DMODEL,
                     Cv, (size_t)bm * 128, (size_t)bn * 64, DMODEL);
}

// ---------------------------- V transpose ----------------------------------
// QKV[(s*BS+b)*3072 + 2048 + h*64 + d] -> Vt[((b*16+h)*64 + d)*2048 + P(s)]
// P permutes within each 64-k block: k = n*16 + l4*4 + r -> l4*16 + n*4 + r,
// so attn's four K=16 V^T frags per lane are 16B-contiguous.
__global__ __launch_bounds__(256) void transpose_v(const __bf16* __restrict__ QKV,
                                                   __bf16* __restrict__ Vt) {
    __shared__ __bf16 t[64][72];
    const int stile = blockIdx.x;
    const int bh = blockIdx.y;
    const int b = bh >> 4, h = bh & 15;
    const int tid = threadIdx.x;
    {
        int sr = tid >> 2, d0 = (tid & 3) * 16;
        const __bf16* src = QKV + ((size_t)((stile * 64 + sr) * BSZ + b) * D3 + 2 * DMODEL + h * 64 + d0);
        *(bf16x8*)&t[sr][d0]     = *(const bf16x8*)src;
        *(bf16x8*)&t[sr][d0 + 8] = *(const bf16x8*)(src + 8);
    }
    __syncthreads();
    {
        int d = tid >> 2, n = tid & 3;     // n = s0/16 within the 64-block
        int s0 = n * 16;
        __bf16* dst = Vt + ((size_t)(bh * 64 + d) * SLEN + stile * 64);
#pragma unroll
        for (int l4g = 0; l4g < 4; l4g++) {
            bf16x4 w;
#pragma unroll
            for (int r = 0; r < 4; r++) w[r] = t[s0 + l4g * 4 + r][d];
            *(bf16x4*)(dst + l4g * 16 + n * 4) = w;
        }
    }
}

// ---------------------------- attention (swapped QK^T) ---------------------
// grid 512; XCD swizzle. QBLK=128 (4 waves x 32 q), KBLK=128 (2x64 halves).
// S^T = mfma(K,Q): lane l15 = q, l4*4+r = k. P stays in registers; PV uses
// K=16 mfma. V^T frags read as 2x b128 (permuted VT k-order), O^T 8B stores.
__global__ __launch_bounds__(256, 2) void attn_fwd(const __bf16* __restrict__ QKV,
                                                   const __bf16* __restrict__ Vt,
                                                   const int* __restrict__ mask,
                                                   const unsigned int* __restrict__ flag,
                                                   __bf16* __restrict__ Attn) {
    __shared__ __bf16 Kt[2][2][64 * 64];   // [buf][kh][k][d]  32 KB
    __shared__ __bf16 Vs[2][2][64 * 64];   // [buf][kh][d][k'] 32 KB
    const int tid = threadIdx.x;
    const int lane = tid & 63, wv = tid >> 6;
    const int l15 = lane & 15, l4 = lane >> 4;
    const int blk = blockIdx.x;
    const int xcd = blk & 7, idx = blk >> 3;
    const int bh = xcd + (idx >> 4) * 8;
    const int qt = idx & 15;
    const int b = bh >> 4, h = bh & 15;
    const bool allones = (*flag != 0u);
    const int srow = lane >> 3;
    const int sbyte = (((lane & 7) ^ srow) << 4);

    // Q fragments (per wave: 32 q-rows x 64 d), B-operand of swapped QK^T
    bf16x8 aq[2][2];
#pragma unroll
    for (int m = 0; m < 2; m++)
#pragma unroll
        for (int kk = 0; kk < 2; kk++) {
            int qrow = qt * 128 + wv * 32 + m * 16 + l15;
            aq[m][kk] = *(const bf16x8*)(QKV + ((size_t)(qrow * BSZ + b) * D3 + h * 64 + kk * 32 + l4 * 8));
        }

    // O^T accumulators: o[m][nd]: col=q(l15, m-tile), row=d(l4*4+r, nd-tile)
    f32x4 o[2][4];
    float lr[2];
#pragma unroll
    for (int m = 0; m < 2; m++) {
#pragma unroll
        for (int nd = 0; nd < 4; nd++)
#pragma unroll
            for (int r = 0; r < 4; r++) o[m][nd][r] = 0.0f;
        lr[m] = 0.0f;
    }

    const char* Kb = (const char*)QKV + ((size_t)b * D3 + DMODEL + h * 64) * 2;
    const char* Vb = (const char*)Vt + ((size_t)bh * 64) * SLEN * 2;

    auto stage = [&](int buf, int kt) {
#pragma unroll
        for (int i = 0; i < 8; i++) {
            int c = wv * 8 + i;  // 0..31
            if (c < 16) {
                int kh = c >> 3, ck = c & 7;
                int krow = kt * 128 + kh * 64 + ck * 8 + srow;
                async16(&Kt[buf][kh][ck * 512],
                        Kb + (size_t)krow * (BSZ * D3 * 2) + sbyte);
            } else {
                int c2 = c - 16;
                int kh = c2 >> 3, ck = c2 & 7;
                int drow = ck * 8 + srow;
                async16(&Vs[buf][kh][ck * 512],
                        Vb + (size_t)drow * (SLEN * 2) + kt * 256 + kh * 128 + sbyte);
            }
        }
    };

    stage(0, 0);
    __syncthreads();
    int cur = 0;

    for (int kt = 0; kt < SLEN / 128; kt++) {
        if (kt + 1 < SLEN / 128) stage(cur ^ 1, kt + 1);

#pragma unroll
        for (int kh = 0; kh < 2; kh++) {
            const __bf16* Kl = Kt[cur][kh];
            const __bf16* Vl = Vs[cur][kh];

            // K fragments (A-operand): rows k = n*16+l15, d = kk*32+l4*8
            bf16x8 bk[4][2];
#pragma unroll
            for (int n = 0; n < 4; n++) {
                int row = n * 16 + l15;
#pragma unroll
                for (int kk = 0; kk < 2; kk++) {
                    int col = (kk * 32 + l4 * 8) ^ ((row & 7) << 3);
                    bk[n][kk] = *(const bf16x8*)&Kl[row * 64 + col];
                }
            }

            // S^T = K Q^T: s[m][n]: col=q(l15), row=k(n*16+l4*4+r)
            f32x4 s[2][4];
#pragma unroll
            for (int m = 0; m < 2; m++)
#pragma unroll
                for (int n = 0; n < 4; n++)
#pragma unroll
                    for (int r = 0; r < 4; r++) s[m][n][r] = 0.0f;
            __builtin_amdgcn_s_setprio(1);
#pragma unroll
            for (int n = 0; n < 4; n++)
#pragma unroll
                for (int kk = 0; kk < 2; kk++)
#pragma unroll
                    for (int m = 0; m < 2; m++)
                        s[m][n] = mfma16(bk[n][kk], aq[m][kk], s[m][n]);
            __builtin_amdgcn_s_setprio(0);

            if (!allones) {
#pragma unroll
                for (int m = 0; m < 2; m++) {
                    int q = qt * 128 + wv * 32 + m * 16 + l15;
#pragma unroll
                    for (int n = 0; n < 4; n++)
#pragma unroll
                        for (int r = 0; r < 4; r++) {
                            int kg = kt * 128 + kh * 64 + n * 16 + l4 * 4 + r;
                            if (mask[(size_t)q * SLEN + kg] == 0) s[m][n][r] = -1e20f;
                        }
                }
            }

            // exp2 (log2e folded into Wq), pack P^T fragments in-register
            bf16x4 pb[2][4];
#pragma unroll
            for (int m = 0; m < 2; m++)
#pragma unroll
                for (int n = 0; n < 4; n++) {
                    float p0 = __builtin_amdgcn_exp2f(s[m][n][0]);
                    float p1 = __builtin_amdgcn_exp2f(s[m][n][1]);
                    float p2 = __builtin_amdgcn_exp2f(s[m][n][2]);
                    float p3 = __builtin_amdgcn_exp2f(s[m][n][3]);
                    lr[m] += (p0 + p1) + (p2 + p3);
                    bf16x4 w;
                    w[0] = (__bf16)p0; w[1] = (__bf16)p1;
                    w[2] = (__bf16)p2; w[3] = (__bf16)p3;
                    pb[m][n] = w;
                }

            // V^T fragments: row d = nd*16+l15; permuted k-order makes the
            // four K=16 frags 2x contiguous b128 reads (h=0: n=0,1; h=1: n=2,3)
            bf16x8 avv[4][2];
#pragma unroll
            for (int nd = 0; nd < 4; nd++) {
                int row = nd * 16 + l15;
#pragma unroll
                for (int hh = 0; hh < 2; hh++) {
                    int col = (l4 * 16 + hh * 8) ^ ((row & 7) << 3);
                    avv[nd][hh] = *(const bf16x8*)&Vl[row * 64 + col];
                }
            }

            // O^T += V^T P^T  (K=16 mfma; B-operand = pb own-lane, no LDS)
            __builtin_amdgcn_s_setprio(1);
#pragma unroll
            for (int n = 0; n < 4; n++) {
#pragma unroll
                for (int nd = 0; nd < 4; nd++) {
                    bf16x4 av = (n & 1)
                        ? __builtin_shufflevector(avv[nd][n >> 1], avv[nd][n >> 1], 4, 5, 6, 7)
                        : __builtin_shufflevector(avv[nd][n >> 1], avv[nd][n >> 1], 0, 1, 2, 3);
#pragma unroll
                    for (int m = 0; m < 2; m++)
                        o[m][nd] = mfma16k16(av, pb[m][n], o[m][nd]);
                }
            }
            __builtin_amdgcn_s_setprio(0);
        }

        __syncthreads();
        cur ^= 1;
    }

    // row-sum: lane has partial for q=l15; reduce across l4 groups
#pragma unroll
    for (int m = 0; m < 2; m++) {
        lr[m] += __shfl_xor(lr[m], 16);
        lr[m] += __shfl_xor(lr[m], 32);
    }

    // normalize + store O^T: per (m, nd): q = l15-based, d = l4*4+r (8B store)
#pragma unroll
    for (int m = 0; m < 2; m++) {
        float inv = 1.0f / lr[m];
        int qrow = qt * 128 + wv * 32 + m * 16 + l15;
#pragma unroll
        for (int nd = 0; nd < 4; nd++) {
            bf16x4 ov;
#pragma unroll
            for (int r = 0; r < 4; r++) ov[r] = (__bf16)(o[m][nd][r] * inv);
            *(bf16x4*)(Attn + ((size_t)(qrow * BSZ + b)) * DMODEL + h * 64 + nd * 16 + l4 * 4) = ov;
        }
    }
}

// ---------------------------- launcher -------------------------------------
extern "C" void kernel_launch(void* const* d_in, const int* in_sizes, int n_in,
                              void* d_out, int out_size, void* d_ws, size_t ws_size,
                              hipStream_t stream) {
    const float* query  = (const float*)d_in[0];
    const float* keys   = (const float*)d_in[1];
    const float* values = (const float*)d_in[2];
    const int*   mask   = (const int*)d_in[3];
    const float* Wq     = (const float*)d_in[4];
    const float* Wk     = (const float*)d_in[5];
    const float* Wv     = (const float*)d_in[6];
    const float* Wo     = (const float*)d_in[7];
    float* out = (float*)d_out;

    char* ws = (char*)d_ws;
    const size_t MB = 1024 * 1024;
    __bf16* XQ   = (__bf16*)(ws + 0);
    __bf16* XK   = (__bf16*)(ws + 8 * MB);
    __bf16* XV   = (__bf16*)(ws + 16 * MB);
    __bf16* WCAT = (__bf16*)(ws + 24 * MB);   // [3072][1024]: Wq|Wk|Wv
    __bf16* WQB  = WCAT;
    __bf16* WKB  = (__bf16*)(ws + 26 * MB);
    __bf16* WVB  = (__bf16*)(ws + 28 * MB);
    __bf16* WOB  = (__bf16*)(ws + 30 * MB);
    __bf16* QKV  = (__bf16*)(ws + 32 * MB);   // [4096][3072] = 24 MB
    __bf16* VT   = (__bf16*)(ws + 0);         // reuse XQ (free after gemm_qkv)
    __bf16* ATT  = (__bf16*)(ws + 8 * MB);    // reuse XK
    unsigned int* flag = (unsigned int*)(ws + 56 * MB);

    (void)hipMemsetAsync(flag, 0xFF, 4, stream);

    const int NTOK = SLEN * BSZ;  // 4096
    const int NBIG = NTOK * DMODEL / 4, NW = DMODEL * DMODEL / 4;
    const float LOG2E = 1.4426950408889634f;
    CvtArgs ca;
    ca.src[0] = query;  ca.dst[0] = XQ;  ca.n4[0] = NBIG; ca.scale[0] = 1.0f;
    ca.src[1] = keys;   ca.dst[1] = XK;  ca.n4[1] = NBIG; ca.scale[1] = 1.0f;
    ca.src[2] = values; ca.dst[2] = XV;  ca.n4[2] = NBIG; ca.scale[2] = 1.0f;
    ca.src[3] = Wq;     ca.dst[3] = WQB; ca.n4[3] = NW;   ca.scale[3] = LOG2E;
    ca.src[4] = Wk;     ca.dst[4] = WKB; ca.n4[4] = NW;   ca.scale[4] = 1.0f;
    ca.src[5] = Wv;     ca.dst[5] = WVB; ca.n4[5] = NW;   ca.scale[5] = 1.0f;
    ca.src[6] = Wo;     ca.dst[6] = WOB; ca.n4[6] = NW;   ca.scale[6] = 1.0f;
    ca.mask = mask; ca.flag = flag; ca.maskn4 = SLEN * SLEN / 4;
    cvt_all<<<dim3(256, 8), 256, 0, stream>>>(ca);

    // fused QKV projection: grid (32, 48) = 1536 blocks (128x64 tiles)
    gemm_qkv<<<dim3(NTOK / 128, D3 / 64), 256, 0, stream>>>(XQ, XK, XV, WCAT, QKV);

    transpose_v<<<dim3(SLEN / 64, BSZ * NHEAD), 256, 0, stream>>>(QKV, VT);

    attn_fwd<<<BSZ * NHEAD * (SLEN / 128), 256, 0, stream>>>(QKV, VT, mask, flag, ATT);

    gemm_out<<<dim3(NTOK / 128, DMODEL / 64), 256, 0, stream>>>(ATT, WOB, out);
}

// Round 16
// 132.215 us; speedup vs baseline: 1.1370x; 1.0231x over previous
//
#include <hip/hip_runtime.h>

// ---------------------------------------------------------------------------
// MultiHeadAttention forward, MI355X (gfx950), bf16 MFMA pipeline. Round 16:
//  - gemm_qkv: m97-style 128x128xBK64 SINGLE-buffered 2-barrier loop (32KB
//    LDS, launch_bounds(256,3) -> 3 blocks/CU at grid 768). R10's 128^2
//    failure was dbuf 64KB @ 2 blocks/CU, not the tile: m97's measured
//    874-912 TF config is exactly this single-buf structure.
//  - gemm_out: proven 128x64x64 dbuf (512 blocks).
//  - attn: R15 swapped-QK^T, in-register P, permuted-VT b128 V-frags (58.5us).
// ---------------------------------------------------------------------------

typedef __attribute__((ext_vector_type(4))) float  f32x4;
typedef __attribute__((ext_vector_type(8))) __bf16 bf16x8;
typedef __attribute__((ext_vector_type(4))) __bf16 bf16x4;
typedef __attribute__((ext_vector_type(4))) short  s16x4;

#define SLEN 2048
#define BSZ  2
#define DMODEL 1024
#define NHEAD 16
#define DHEAD 64
#define D3 (3 * DMODEL)   // 3072

__device__ __forceinline__ void async16(void* lds, const void* g) {
    __builtin_amdgcn_global_load_lds(
        (const __attribute__((address_space(1))) unsigned int*)g,
        (__attribute__((address_space(3))) unsigned int*)lds, 16, 0, 0);
}

__device__ __forceinline__ f32x4 mfma16(bf16x8 a, bf16x8 b, f32x4 c) {
    return __builtin_amdgcn_mfma_f32_16x16x32_bf16(a, b, c, 0, 0, 0);
}

// K=16 variant: A/B = 4 bf16 (2 VGPR).
__device__ __forceinline__ f32x4 mfma16k16(bf16x4 a, bf16x4 b, f32x4 c) {
#if __has_builtin(__builtin_amdgcn_mfma_f32_16x16x16_bf16)
    return __builtin_amdgcn_mfma_f32_16x16x16_bf16(a, b, c, 0, 0, 0);
#else
    return __builtin_amdgcn_mfma_f32_16x16x16bf16_1k(
        __builtin_bit_cast(s16x4, a), __builtin_bit_cast(s16x4, b), c, 0, 0, 0);
#endif
}

// ------------------- fused convert fp32 -> bf16 (+ mask flag) --------------
struct CvtArgs {
    const float* src[7];
    __bf16* dst[7];
    int n4[7];
    float scale[7];
    const int* mask;
    unsigned int* flag;
    int maskn4;
};
__global__ void cvt_all(CvtArgs a) {
    const int t = blockIdx.y;
    const int stride = gridDim.x * blockDim.x;
    if (t == 7) {
        bool ok = true;
        for (int i = blockIdx.x * blockDim.x + threadIdx.x; i < a.maskn4; i += stride) {
            int4 v = ((const int4*)a.mask)[i];
            ok = ok && v.x && v.y && v.z && v.w;
        }
        if (!ok) atomicAnd(a.flag, 0u);
        return;
    }
    const float* __restrict__ src = a.src[t];
    __bf16* __restrict__ dst = a.dst[t];
    const int n4 = a.n4[t];
    const float sc = a.scale[t];
    for (int i = blockIdx.x * blockDim.x + threadIdx.x; i < n4; i += stride) {
        float4 v = ((const float4*)src)[i];
        bf16x4 o;
        o[0] = (__bf16)(v.x * sc); o[1] = (__bf16)(v.y * sc);
        o[2] = (__bf16)(v.z * sc); o[3] = (__bf16)(v.w * sc);
        ((bf16x4*)dst)[i] = o;
    }
}

// ------------------- gemm_qkv: 128x128xBK64, single-buf m97 loop -----------
// 256 threads (4 waves 2x2), per-wave 64x64 out. LDS 32KB. bn 0..23.
__global__ __launch_bounds__(256, 3) void gemm_qkv(const __bf16* __restrict__ Xq,
                                                   const __bf16* __restrict__ Xk,
                                                   const __bf16* __restrict__ Xv,
                                                   const __bf16* __restrict__ W,
                                                   __bf16* __restrict__ C) {
    __shared__ __bf16 At[128 * 64];
    __shared__ __bf16 Bt[128 * 64];
    const int tid = threadIdx.x;
    const int lane = tid & 63, wv = tid >> 6;
    const int l15 = lane & 15, l4 = lane >> 4;
    const int wr = wv >> 1, wc = wv & 1;
    const int srow = lane >> 3;
    const int sbyte = (((lane & 7) ^ srow) << 4);
    const int bm = blockIdx.x, bn = blockIdx.y;
    const __bf16* A = (bn < 8) ? Xq : (bn < 16) ? Xk : Xv;
    const char* Ab = (const char*)(A + (size_t)bm * 128 * DMODEL);
    const char* Bb = (const char*)(W + (size_t)bn * 128 * DMODEL);

    f32x4 acc[4][4];
#pragma unroll
    for (int m = 0; m < 4; m++)
#pragma unroll
        for (int n = 0; n < 4; n++)
#pragma unroll
            for (int r = 0; r < 4; r++) acc[m][n][r] = 0.0f;

    for (int k0 = 0; k0 < DMODEL; k0 += 64) {
        __syncthreads();
        // stage 32 KB: A 16 chunks + B 16 chunks of 1KB; 8 per wave
#pragma unroll
        for (int i = 0; i < 8; i++) {
            int c = wv * 8 + i;
            if (c < 16) {
                int row = c * 8 + srow;
                async16(&At[c * 512], Ab + ((size_t)row * DMODEL + k0) * 2 + sbyte);
            } else {
                int row = (c - 16) * 8 + srow;
                async16(&Bt[(c - 16) * 512], Bb + ((size_t)row * DMODEL + k0) * 2 + sbyte);
            }
        }
        __syncthreads();

#pragma unroll
        for (int kk = 0; kk < 2; kk++) {
            bf16x8 af[4], bfr[4];
#pragma unroll
            for (int m = 0; m < 4; m++) {
                int row = wr * 64 + m * 16 + l15;
                int col = (kk * 32 + l4 * 8) ^ ((row & 7) << 3);
                af[m] = *(const bf16x8*)&At[row * 64 + col];
            }
#pragma unroll
            for (int n = 0; n < 4; n++) {
                int row = wc * 64 + n * 16 + l15;
                int col = (kk * 32 + l4 * 8) ^ ((row & 7) << 3);
                bfr[n] = *(const bf16x8*)&Bt[row * 64 + col];
            }
#pragma unroll
            for (int m = 0; m < 4; m++)
#pragma unroll
                for (int n = 0; n < 4; n++)
                    acc[m][n] = mfma16(af[m], bfr[n], acc[m][n]);
        }
    }

#pragma unroll
    for (int m = 0; m < 4; m++)
#pragma unroll
        for (int n = 0; n < 4; n++)
#pragma unroll
            for (int r = 0; r < 4; r++) {
                size_t row = (size_t)bm * 128 + wr * 64 + m * 16 + l4 * 4 + r;
                size_t col = (size_t)bn * 128 + wc * 64 + n * 16 + l15;
                C[row * D3 + col] = (__bf16)acc[m][n][r];
            }
}

// ---------------------------- gemm_out: 128x64x64 dbuf ---------------------
__global__ __launch_bounds__(256, 2) void gemm_out(const __bf16* __restrict__ A,
                                                   const __bf16* __restrict__ B,
                                                   float* __restrict__ Cv) {
    __shared__ __bf16 At[2][128 * 64];
    __shared__ __bf16 Bt[2][64 * 64];
    const int tid = threadIdx.x;
    const int lane = tid & 63, wv = tid >> 6;
    const int l15 = lane & 15, l4 = lane >> 4;
    const int wr = wv >> 1, wc = wv & 1;
    const int srow = lane >> 3;
    const int sbyte = (((lane & 7) ^ srow) << 4);
    const int bm = blockIdx.x, bn = blockIdx.y;
    const char* Ab = (const char*)(A + (size_t)bm * 128 * DMODEL);
    const char* Bb = (const char*)(B + (size_t)bn * 64 * DMODEL);

    f32x4 acc[4][2];
#pragma unroll
    for (int m = 0; m < 4; m++)
#pragma unroll
        for (int n = 0; n < 2; n++)
#pragma unroll
            for (int r = 0; r < 4; r++) acc[m][n][r] = 0.0f;

    auto stage = [&](int buf, int k0) {
#pragma unroll
        for (int i = 0; i < 6; i++) {
            int c = wv * 6 + i;
            if (c < 16) {
                int row = c * 8 + srow;
                async16(&At[buf][c * 512], Ab + ((size_t)row * DMODEL + k0) * 2 + sbyte);
            } else {
                int row = (c - 16) * 8 + srow;
                async16(&Bt[buf][(c - 16) * 512], Bb + ((size_t)row * DMODEL + k0) * 2 + sbyte);
            }
        }
    };

    stage(0, 0);
    __syncthreads();
    int cur = 0;
    for (int k0 = 0; k0 < DMODEL; k0 += 64) {
        if (k0 + 64 < DMODEL) stage(cur ^ 1, k0 + 64);
#pragma unroll
        for (int kk = 0; kk < 2; kk++) {
            bf16x8 af[4], bfr[2];
#pragma unroll
            for (int m = 0; m < 4; m++) {
                int row = wr * 64 + m * 16 + l15;
                int col = (kk * 32 + l4 * 8) ^ ((row & 7) << 3);
                af[m] = *(const bf16x8*)&At[cur][row * 64 + col];
            }
#pragma unroll
            for (int n = 0; n < 2; n++) {
                int row = wc * 32 + n * 16 + l15;
                int col = (kk * 32 + l4 * 8) ^ ((row & 7) << 3);
                bfr[n] = *(const bf16x8*)&Bt[cur][row * 64 + col];
            }
#pragma unroll
            for (int m = 0; m < 4; m++)
#pragma unroll
                for (int n = 0; n < 2; n++)
                    acc[m][n] = mfma16(af[m], bfr[n], acc[m][n]);
        }
        __syncthreads();
        cur ^= 1;
    }

#pragma unroll
    for (int m = 0; m < 4; m++)
#pragma unroll
        for (int n = 0; n < 2; n++)
#pragma unroll
            for (int r = 0; r < 4; r++) {
                size_t row = (size_t)bm * 128 + wr * 64 + m * 16 + l4 * 4 + r;
                size_t col = (size_t)bn * 64 + wc * 32 + n * 16 + l15;
                Cv[row * DMODEL + col] = acc[m][n][r];
            }
}

// ---------------------------- V transpose (permuted k-order) ---------------
__global__ __launch_bounds__(256) void transpose_v(const __bf16* __restrict__ QKV,
                                                   __bf16* __restrict__ Vt) {
    __shared__ __bf16 t[64][72];
    const int stile = blockIdx.x;
    const int bh = blockIdx.y;
    const int b = bh >> 4, h = bh & 15;
    const int tid = threadIdx.x;
    {
        int sr = tid >> 2, d0 = (tid & 3) * 16;
        const __bf16* src = QKV + ((size_t)((stile * 64 + sr) * BSZ + b) * D3 + 2 * DMODEL + h * 64 + d0);
        *(bf16x8*)&t[sr][d0]     = *(const bf16x8*)src;
        *(bf16x8*)&t[sr][d0 + 8] = *(const bf16x8*)(src + 8);
    }
    __syncthreads();
    {
        int d = tid >> 2, n = tid & 3;
        int s0 = n * 16;
        __bf16* dst = Vt + ((size_t)(bh * 64 + d) * SLEN + stile * 64);
#pragma unroll
        for (int l4g = 0; l4g < 4; l4g++) {
            bf16x4 w;
#pragma unroll
            for (int r = 0; r < 4; r++) w[r] = t[s0 + l4g * 4 + r][d];
            *(bf16x4*)(dst + l4g * 16 + n * 4) = w;
        }
    }
}

// ---------------------------- attention (swapped QK^T) ---------------------
__global__ __launch_bounds__(256, 2) void attn_fwd(const __bf16* __restrict__ QKV,
                                                   const __bf16* __restrict__ Vt,
                                                   const int* __restrict__ mask,
                                                   const unsigned int* __restrict__ flag,
                                                   __bf16* __restrict__ Attn) {
    __shared__ __bf16 Kt[2][2][64 * 64];
    __shared__ __bf16 Vs[2][2][64 * 64];
    const int tid = threadIdx.x;
    const int lane = tid & 63, wv = tid >> 6;
    const int l15 = lane & 15, l4 = lane >> 4;
    const int blk = blockIdx.x;
    const int xcd = blk & 7, idx = blk >> 3;
    const int bh = xcd + (idx >> 4) * 8;
    const int qt = idx & 15;
    const int b = bh >> 4, h = bh & 15;
    const bool allones = (*flag != 0u);
    const int srow = lane >> 3;
    const int sbyte = (((lane & 7) ^ srow) << 4);

    bf16x8 aq[2][2];
#pragma unroll
    for (int m = 0; m < 2; m++)
#pragma unroll
        for (int kk = 0; kk < 2; kk++) {
            int qrow = qt * 128 + wv * 32 + m * 16 + l15;
            aq[m][kk] = *(const bf16x8*)(QKV + ((size_t)(qrow * BSZ + b) * D3 + h * 64 + kk * 32 + l4 * 8));
        }

    f32x4 o[2][4];
    float lr[2];
#pragma unroll
    for (int m = 0; m < 2; m++) {
#pragma unroll
        for (int nd = 0; nd < 4; nd++)
#pragma unroll
            for (int r = 0; r < 4; r++) o[m][nd][r] = 0.0f;
        lr[m] = 0.0f;
    }

    const char* Kb = (const char*)QKV + ((size_t)b * D3 + DMODEL + h * 64) * 2;
    const char* Vb = (const char*)Vt + ((size_t)bh * 64) * SLEN * 2;

    auto stage = [&](int buf, int kt) {
#pragma unroll
        for (int i = 0; i < 8; i++) {
            int c = wv * 8 + i;
            if (c < 16) {
                int kh = c >> 3, ck = c & 7;
                int krow = kt * 128 + kh * 64 + ck * 8 + srow;
                async16(&Kt[buf][kh][ck * 512],
                        Kb + (size_t)krow * (BSZ * D3 * 2) + sbyte);
            } else {
                int c2 = c - 16;
                int kh = c2 >> 3, ck = c2 & 7;
                int drow = ck * 8 + srow;
                async16(&Vs[buf][kh][ck * 512],
                        Vb + (size_t)drow * (SLEN * 2) + kt * 256 + kh * 128 + sbyte);
            }
        }
    };

    stage(0, 0);
    __syncthreads();
    int cur = 0;

    for (int kt = 0; kt < SLEN / 128; kt++) {
        if (kt + 1 < SLEN / 128) stage(cur ^ 1, kt + 1);

#pragma unroll
        for (int kh = 0; kh < 2; kh++) {
            const __bf16* Kl = Kt[cur][kh];
            const __bf16* Vl = Vs[cur][kh];

            bf16x8 bk[4][2];
#pragma unroll
            for (int n = 0; n < 4; n++) {
                int row = n * 16 + l15;
#pragma unroll
                for (int kk = 0; kk < 2; kk++) {
                    int col = (kk * 32 + l4 * 8) ^ ((row & 7) << 3);
                    bk[n][kk] = *(const bf16x8*)&Kl[row * 64 + col];
                }
            }

            f32x4 s[2][4];
#pragma unroll
            for (int m = 0; m < 2; m++)
#pragma unroll
                for (int n = 0; n < 4; n++)
#pragma unroll
                    for (int r = 0; r < 4; r++) s[m][n][r] = 0.0f;
            __builtin_amdgcn_s_setprio(1);
#pragma unroll
            for (int n = 0; n < 4; n++)
#pragma unroll
                for (int kk = 0; kk < 2; kk++)
#pragma unroll
                    for (int m = 0; m < 2; m++)
                        s[m][n] = mfma16(bk[n][kk], aq[m][kk], s[m][n]);
            __builtin_amdgcn_s_setprio(0);

            if (!allones) {
#pragma unroll
                for (int m = 0; m < 2; m++) {
                    int q = qt * 128 + wv * 32 + m * 16 + l15;
#pragma unroll
                    for (int n = 0; n < 4; n++)
#pragma unroll
                        for (int r = 0; r < 4; r++) {
                            int kg = kt * 128 + kh * 64 + n * 16 + l4 * 4 + r;
                            if (mask[(size_t)q * SLEN + kg] == 0) s[m][n][r] = -1e20f;
                        }
                }
            }

            bf16x4 pb[2][4];
#pragma unroll
            for (int m = 0; m < 2; m++)
#pragma unroll
                for (int n = 0; n < 4; n++) {
                    float p0 = __builtin_amdgcn_exp2f(s[m][n][0]);
                    float p1 = __builtin_amdgcn_exp2f(s[m][n][1]);
                    float p2 = __builtin_amdgcn_exp2f(s[m][n][2]);
                    float p3 = __builtin_amdgcn_exp2f(s[m][n][3]);
                    lr[m] += (p0 + p1) + (p2 + p3);
                    bf16x4 w;
                    w[0] = (__bf16)p0; w[1] = (__bf16)p1;
                    w[2] = (__bf16)p2; w[3] = (__bf16)p3;
                    pb[m][n] = w;
                }

            bf16x8 avv[4][2];
#pragma unroll
            for (int nd = 0; nd < 4; nd++) {
                int row = nd * 16 + l15;
#pragma unroll
                for (int hh = 0; hh < 2; hh++) {
                    int col = (l4 * 16 + hh * 8) ^ ((row & 7) << 3);
                    avv[nd][hh] = *(const bf16x8*)&Vl[row * 64 + col];
                }
            }

            __builtin_amdgcn_s_setprio(1);
#pragma unroll
            for (int n = 0; n < 4; n++) {
#pragma unroll
                for (int nd = 0; nd < 4; nd++) {
                    bf16x4 av = (n & 1)
                        ? __builtin_shufflevector(avv[nd][n >> 1], avv[nd][n >> 1], 4, 5, 6, 7)
                        : __builtin_shufflevector(avv[nd][n >> 1], avv[nd][n >> 1], 0, 1, 2, 3);
#pragma unroll
                    for (int m = 0; m < 2; m++)
                        o[m][nd] = mfma16k16(av, pb[m][n], o[m][nd]);
                }
            }
            __builtin_amdgcn_s_setprio(0);
        }

        __syncthreads();
        cur ^= 1;
    }

#pragma unroll
    for (int m = 0; m < 2; m++) {
        lr[m] += __shfl_xor(lr[m], 16);
        lr[m] += __shfl_xor(lr[m], 32);
    }

#pragma unroll
    for (int m = 0; m < 2; m++) {
        float inv = 1.0f / lr[m];
        int qrow = qt * 128 + wv * 32 + m * 16 + l15;
#pragma unroll
        for (int nd = 0; nd < 4; nd++) {
            bf16x4 ov;
#pragma unroll
            for (int r = 0; r < 4; r++) ov[r] = (__bf16)(o[m][nd][r] * inv);
            *(bf16x4*)(Attn + ((size_t)(qrow * BSZ + b)) * DMODEL + h * 64 + nd * 16 + l4 * 4) = ov;
        }
    }
}

// ---------------------------- launcher -------------------------------------
extern "C" void kernel_launch(void* const* d_in, const int* in_sizes, int n_in,
                              void* d_out, int out_size, void* d_ws, size_t ws_size,
                              hipStream_t stream) {
    const float* query  = (const float*)d_in[0];
    const float* keys   = (const float*)d_in[1];
    const float* values = (const float*)d_in[2];
    const int*   mask   = (const int*)d_in[3];
    const float* Wq     = (const float*)d_in[4];
    const float* Wk     = (const float*)d_in[5];
    const float* Wv     = (const float*)d_in[6];
    const float* Wo     = (const float*)d_in[7];
    float* out = (float*)d_out;

    char* ws = (char*)d_ws;
    const size_t MB = 1024 * 1024;
    __bf16* XQ   = (__bf16*)(ws + 0);
    __bf16* XK   = (__bf16*)(ws + 8 * MB);
    __bf16* XV   = (__bf16*)(ws + 16 * MB);
    __bf16* WCAT = (__bf16*)(ws + 24 * MB);   // [3072][1024]: Wq|Wk|Wv
    __bf16* WQB  = WCAT;
    __bf16* WKB  = (__bf16*)(ws + 26 * MB);
    __bf16* WVB  = (__bf16*)(ws + 28 * MB);
    __bf16* WOB  = (__bf16*)(ws + 30 * MB);
    __bf16* QKV  = (__bf16*)(ws + 32 * MB);   // [4096][3072] = 24 MB
    __bf16* VT   = (__bf16*)(ws + 0);         // reuse XQ (free after gemm_qkv)
    __bf16* ATT  = (__bf16*)(ws + 8 * MB);    // reuse XK
    unsigned int* flag = (unsigned int*)(ws + 56 * MB);

    (void)hipMemsetAsync(flag, 0xFF, 4, stream);

    const int NTOK = SLEN * BSZ;  // 4096
    const int NBIG = NTOK * DMODEL / 4, NW = DMODEL * DMODEL / 4;
    const float LOG2E = 1.4426950408889634f;
    CvtArgs ca;
    ca.src[0] = query;  ca.dst[0] = XQ;  ca.n4[0] = NBIG; ca.scale[0] = 1.0f;
    ca.src[1] = keys;   ca.dst[1] = XK;  ca.n4[1] = NBIG; ca.scale[1] = 1.0f;
    ca.src[2] = values; ca.dst[2] = XV;  ca.n4[2] = NBIG; ca.scale[2] = 1.0f;
    ca.src[3] = Wq;     ca.dst[3] = WQB; ca.n4[3] = NW;   ca.scale[3] = LOG2E;
    ca.src[4] = Wk;     ca.dst[4] = WKB; ca.n4[4] = NW;   ca.scale[4] = 1.0f;
    ca.src[5] = Wv;     ca.dst[5] = WVB; ca.n4[5] = NW;   ca.scale[5] = 1.0f;
    ca.src[6] = Wo;     ca.dst[6] = WOB; ca.n4[6] = NW;   ca.scale[6] = 1.0f;
    ca.mask = mask; ca.flag = flag; ca.maskn4 = SLEN * SLEN / 4;
    cvt_all<<<dim3(256, 8), 256, 0, stream>>>(ca);

    // fused QKV projection: grid (32, 24) = 768 blocks (128x128 single-buf)
    gemm_qkv<<<dim3(NTOK / 128, D3 / 128), 256, 0, stream>>>(XQ, XK, XV, WCAT, QKV);

    transpose_v<<<dim3(SLEN / 64, BSZ * NHEAD), 256, 0, stream>>>(QKV, VT);

    attn_fwd<<<BSZ * NHEAD * (SLEN / 128), 256, 0, stream>>>(QKV, VT, mask, flag, ATT);

    gemm_out<<<dim3(NTOK / 128, DMODEL / 64), 256, 0, stream>>>(ATT, WOB, out);
}

// Round 17
// 122.946 us; speedup vs baseline: 1.2227x; 1.0754x over previous
//
#include <hip/hip_runtime.h>

// ---------------------------------------------------------------------------
// MultiHeadAttention forward, MI355X (gfx950), bf16 MFMA pipeline. Round 17:
//  - attn: K-staging ROW-PERMUTED (pi(p) = (p&32) + ((p&12)<<1) + (((p>>4)&1)<<2)
//    + (p&3)) so S^T positions give k = half*32 + l4*8 + j per lane -> P^T
//    packs directly into K=32 B-fragments. PV: 16x mfma_16x16x32 (was 32x
//    K=16 at half efficiency). VT back to identity transpose; avv reads take
//    the bk-style (half*32+l4*8)^swz b128 form (0-conflict pattern).
//  - gemm_qkv: 128^2xBK64 single-buf (R16, best). gemm_out: 128x64 dbuf.
// ---------------------------------------------------------------------------

typedef __attribute__((ext_vector_type(4))) float  f32x4;
typedef __attribute__((ext_vector_type(8))) __bf16 bf16x8;
typedef __attribute__((ext_vector_type(4))) __bf16 bf16x4;

#define SLEN 2048
#define BSZ  2
#define DMODEL 1024
#define NHEAD 16
#define DHEAD 64
#define D3 (3 * DMODEL)   // 3072

__device__ __forceinline__ void async16(void* lds, const void* g) {
    __builtin_amdgcn_global_load_lds(
        (const __attribute__((address_space(1))) unsigned int*)g,
        (__attribute__((address_space(3))) unsigned int*)lds, 16, 0, 0);
}

__device__ __forceinline__ f32x4 mfma16(bf16x8 a, bf16x8 b, f32x4 c) {
    return __builtin_amdgcn_mfma_f32_16x16x32_bf16(a, b, c, 0, 0, 0);
}

// ------------------- fused convert fp32 -> bf16 (+ mask flag) --------------
struct CvtArgs {
    const float* src[7];
    __bf16* dst[7];
    int n4[7];
    float scale[7];
    const int* mask;
    unsigned int* flag;
    int maskn4;
};
__global__ void cvt_all(CvtArgs a) {
    const int t = blockIdx.y;
    const int stride = gridDim.x * blockDim.x;
    if (t == 7) {
        bool ok = true;
        for (int i = blockIdx.x * blockDim.x + threadIdx.x; i < a.maskn4; i += stride) {
            int4 v = ((const int4*)a.mask)[i];
            ok = ok && v.x && v.y && v.z && v.w;
        }
        if (!ok) atomicAnd(a.flag, 0u);
        return;
    }
    const float* __restrict__ src = a.src[t];
    __bf16* __restrict__ dst = a.dst[t];
    const int n4 = a.n4[t];
    const float sc = a.scale[t];
    for (int i = blockIdx.x * blockDim.x + threadIdx.x; i < n4; i += stride) {
        float4 v = ((const float4*)src)[i];
        bf16x4 o;
        o[0] = (__bf16)(v.x * sc); o[1] = (__bf16)(v.y * sc);
        o[2] = (__bf16)(v.z * sc); o[3] = (__bf16)(v.w * sc);
        ((bf16x4*)dst)[i] = o;
    }
}

// ------------------- gemm_qkv: 128x128xBK64, single-buf m97 loop -----------
__global__ __launch_bounds__(256, 3) void gemm_qkv(const __bf16* __restrict__ Xq,
                                                   const __bf16* __restrict__ Xk,
                                                   const __bf16* __restrict__ Xv,
                                                   const __bf16* __restrict__ W,
                                                   __bf16* __restrict__ C) {
    __shared__ __bf16 At[128 * 64];
    __shared__ __bf16 Bt[128 * 64];
    const int tid = threadIdx.x;
    const int lane = tid & 63, wv = tid >> 6;
    const int l15 = lane & 15, l4 = lane >> 4;
    const int wr = wv >> 1, wc = wv & 1;
    const int srow = lane >> 3;
    const int sbyte = (((lane & 7) ^ srow) << 4);
    const int bm = blockIdx.x, bn = blockIdx.y;
    const __bf16* A = (bn < 8) ? Xq : (bn < 16) ? Xk : Xv;
    const char* Ab = (const char*)(A + (size_t)bm * 128 * DMODEL);
    const char* Bb = (const char*)(W + (size_t)bn * 128 * DMODEL);

    f32x4 acc[4][4];
#pragma unroll
    for (int m = 0; m < 4; m++)
#pragma unroll
        for (int n = 0; n < 4; n++)
#pragma unroll
            for (int r = 0; r < 4; r++) acc[m][n][r] = 0.0f;

    for (int k0 = 0; k0 < DMODEL; k0 += 64) {
        __syncthreads();
#pragma unroll
        for (int i = 0; i < 8; i++) {
            int c = wv * 8 + i;
            if (c < 16) {
                int row = c * 8 + srow;
                async16(&At[c * 512], Ab + ((size_t)row * DMODEL + k0) * 2 + sbyte);
            } else {
                int row = (c - 16) * 8 + srow;
                async16(&Bt[(c - 16) * 512], Bb + ((size_t)row * DMODEL + k0) * 2 + sbyte);
            }
        }
        __syncthreads();

#pragma unroll
        for (int kk = 0; kk < 2; kk++) {
            bf16x8 af[4], bfr[4];
#pragma unroll
            for (int m = 0; m < 4; m++) {
                int row = wr * 64 + m * 16 + l15;
                int col = (kk * 32 + l4 * 8) ^ ((row & 7) << 3);
                af[m] = *(const bf16x8*)&At[row * 64 + col];
            }
#pragma unroll
            for (int n = 0; n < 4; n++) {
                int row = wc * 64 + n * 16 + l15;
                int col = (kk * 32 + l4 * 8) ^ ((row & 7) << 3);
                bfr[n] = *(const bf16x8*)&Bt[row * 64 + col];
            }
#pragma unroll
            for (int m = 0; m < 4; m++)
#pragma unroll
                for (int n = 0; n < 4; n++)
                    acc[m][n] = mfma16(af[m], bfr[n], acc[m][n]);
        }
    }

#pragma unroll
    for (int m = 0; m < 4; m++)
#pragma unroll
        for (int n = 0; n < 4; n++)
#pragma unroll
            for (int r = 0; r < 4; r++) {
                size_t row = (size_t)bm * 128 + wr * 64 + m * 16 + l4 * 4 + r;
                size_t col = (size_t)bn * 128 + wc * 64 + n * 16 + l15;
                C[row * D3 + col] = (__bf16)acc[m][n][r];
            }
}

// ---------------------------- gemm_out: 128x64x64 dbuf ---------------------
__global__ __launch_bounds__(256, 2) void gemm_out(const __bf16* __restrict__ A,
                                                   const __bf16* __restrict__ B,
                                                   float* __restrict__ Cv) {
    __shared__ __bf16 At[2][128 * 64];
    __shared__ __bf16 Bt[2][64 * 64];
    const int tid = threadIdx.x;
    const int lane = tid & 63, wv = tid >> 6;
    const int l15 = lane & 15, l4 = lane >> 4;
    const int wr = wv >> 1, wc = wv & 1;
    const int srow = lane >> 3;
    const int sbyte = (((lane & 7) ^ srow) << 4);
    const int bm = blockIdx.x, bn = blockIdx.y;
    const char* Ab = (const char*)(A + (size_t)bm * 128 * DMODEL);
    const char* Bb = (const char*)(B + (size_t)bn * 64 * DMODEL);

    f32x4 acc[4][2];
#pragma unroll
    for (int m = 0; m < 4; m++)
#pragma unroll
        for (int n = 0; n < 2; n++)
#pragma unroll
            for (int r = 0; r < 4; r++) acc[m][n][r] = 0.0f;

    auto stage = [&](int buf, int k0) {
#pragma unroll
        for (int i = 0; i < 6; i++) {
            int c = wv * 6 + i;
            if (c < 16) {
                int row = c * 8 + srow;
                async16(&At[buf][c * 512], Ab + ((size_t)row * DMODEL + k0) * 2 + sbyte);
            } else {
                int row = (c - 16) * 8 + srow;
                async16(&Bt[buf][(c - 16) * 512], Bb + ((size_t)row * DMODEL + k0) * 2 + sbyte);
            }
        }
    };

    stage(0, 0);
    __syncthreads();
    int cur = 0;
    for (int k0 = 0; k0 < DMODEL; k0 += 64) {
        if (k0 + 64 < DMODEL) stage(cur ^ 1, k0 + 64);
#pragma unroll
        for (int kk = 0; kk < 2; kk++) {
            bf16x8 af[4], bfr[2];
#pragma unroll
            for (int m = 0; m < 4; m++) {
                int row = wr * 64 + m * 16 + l15;
                int col = (kk * 32 + l4 * 8) ^ ((row & 7) << 3);
                af[m] = *(const bf16x8*)&At[cur][row * 64 + col];
            }
#pragma unroll
            for (int n = 0; n < 2; n++) {
                int row = wc * 32 + n * 16 + l15;
                int col = (kk * 32 + l4 * 8) ^ ((row & 7) << 3);
                bfr[n] = *(const bf16x8*)&Bt[cur][row * 64 + col];
            }
#pragma unroll
            for (int m = 0; m < 4; m++)
#pragma unroll
                for (int n = 0; n < 2; n++)
                    acc[m][n] = mfma16(af[m], bfr[n], acc[m][n]);
        }
        __syncthreads();
        cur ^= 1;
    }

#pragma unroll
    for (int m = 0; m < 4; m++)
#pragma unroll
        for (int n = 0; n < 2; n++)
#pragma unroll
            for (int r = 0; r < 4; r++) {
                size_t row = (size_t)bm * 128 + wr * 64 + m * 16 + l4 * 4 + r;
                size_t col = (size_t)bn * 64 + wc * 32 + n * 16 + l15;
                Cv[row * DMODEL + col] = acc[m][n][r];
            }
}

// ---------------------------- V transpose (identity k-order) ---------------
// QKV[(s*BS+b)*3072 + 2048 + h*64 + d]  ->  Vt[((b*16+h)*64 + d)*2048 + s]
__global__ __launch_bounds__(256) void transpose_v(const __bf16* __restrict__ QKV,
                                                   __bf16* __restrict__ Vt) {
    __shared__ __bf16 t[64][72];
    const int stile = blockIdx.x;
    const int bh = blockIdx.y;
    const int b = bh >> 4, h = bh & 15;
    const int tid = threadIdx.x;
    {
        int sr = tid >> 2, d0 = (tid & 3) * 16;
        const __bf16* src = QKV + ((size_t)((stile * 64 + sr) * BSZ + b) * D3 + 2 * DMODEL + h * 64 + d0);
        *(bf16x8*)&t[sr][d0]     = *(const bf16x8*)src;
        *(bf16x8*)&t[sr][d0 + 8] = *(const bf16x8*)(src + 8);
    }
    __syncthreads();
    {
        int d = tid >> 2, s0 = (tid & 3) * 16;
        bf16x8 o1, o2;
#pragma unroll
        for (int j = 0; j < 8; j++) { o1[j] = t[s0 + j][d]; o2[j] = t[s0 + 8 + j][d]; }
        __bf16* dst = Vt + ((size_t)(bh * 64 + d) * SLEN + stile * 64 + s0);
        *(bf16x8*)dst = o1;
        *(bf16x8*)(dst + 8) = o2;
    }
}

// ---------------------------- attention (perm-K, K=32 PV) ------------------
// grid 512; XCD swizzle. QBLK=128, KBLK=128 (2x64 halves), dbuf 64KB.
// K rows staged permuted: LDS position p holds true k = pi(p),
// pi(p) = (p&32) + ((p&12)<<1) + (((p>>4)&1)<<2) + (p&3).
// => s[m][n][r] (lane l4) holds k = (n>>1)*32 + l4*8 + (n&1)*4 + r,
// so P^T packs into K=32 B-frags own-lane; PV = 16x mfma_16x16x32.
__global__ __launch_bounds__(256, 2) void attn_fwd(const __bf16* __restrict__ QKV,
                                                   const __bf16* __restrict__ Vt,
                                                   const int* __restrict__ mask,
                                                   const unsigned int* __restrict__ flag,
                                                   __bf16* __restrict__ Attn) {
    __shared__ __bf16 Kt[2][2][64 * 64];
    __shared__ __bf16 Vs[2][2][64 * 64];
    const int tid = threadIdx.x;
    const int lane = tid & 63, wv = tid >> 6;
    const int l15 = lane & 15, l4 = lane >> 4;
    const int blk = blockIdx.x;
    const int xcd = blk & 7, idx = blk >> 3;
    const int bh = xcd + (idx >> 4) * 8;
    const int qt = idx & 15;
    const int b = bh >> 4, h = bh & 15;
    const bool allones = (*flag != 0u);
    const int srow = lane >> 3;
    const int sbyte = (((lane & 7) ^ srow) << 4);

    bf16x8 aq[2][2];
#pragma unroll
    for (int m = 0; m < 2; m++)
#pragma unroll
        for (int kk = 0; kk < 2; kk++) {
            int qrow = qt * 128 + wv * 32 + m * 16 + l15;
            aq[m][kk] = *(const bf16x8*)(QKV + ((size_t)(qrow * BSZ + b) * D3 + h * 64 + kk * 32 + l4 * 8));
        }

    f32x4 o[2][4];
    float lr[2];
#pragma unroll
    for (int m = 0; m < 2; m++) {
#pragma unroll
        for (int nd = 0; nd < 4; nd++)
#pragma unroll
            for (int r = 0; r < 4; r++) o[m][nd][r] = 0.0f;
        lr[m] = 0.0f;
    }

    const char* Kb = (const char*)QKV + ((size_t)b * D3 + DMODEL + h * 64) * 2;
    const char* Vb = (const char*)Vt + ((size_t)bh * 64) * SLEN * 2;

    auto stage = [&](int buf, int kt) {
#pragma unroll
        for (int i = 0; i < 8; i++) {
            int c = wv * 8 + i;
            if (c < 16) {
                int kh = c >> 3, ck = c & 7;
                int p = (ck & 7) * 8 + srow;  // LDS position within 64-block
                int kperm = (p & 32) + ((p & 12) << 1) + (((p >> 4) & 1) << 2) + (p & 3);
                int krow = kt * 128 + kh * 64 + kperm;
                async16(&Kt[buf][kh][ck * 512],
                        Kb + (size_t)krow * (BSZ * D3 * 2) + sbyte);
            } else {
                int c2 = c - 16;
                int kh = c2 >> 3, ck = c2 & 7;
                int drow = ck * 8 + srow;
                async16(&Vs[buf][kh][ck * 512],
                        Vb + (size_t)drow * (SLEN * 2) + kt * 256 + kh * 128 + sbyte);
            }
        }
    };

    stage(0, 0);
    __syncthreads();
    int cur = 0;

    for (int kt = 0; kt < SLEN / 128; kt++) {
        if (kt + 1 < SLEN / 128) stage(cur ^ 1, kt + 1);

#pragma unroll
        for (int kh = 0; kh < 2; kh++) {
            const __bf16* Kl = Kt[cur][kh];
            const __bf16* Vl = Vs[cur][kh];

            bf16x8 bk[4][2];
#pragma unroll
            for (int n = 0; n < 4; n++) {
                int row = n * 16 + l15;
#pragma unroll
                for (int kk = 0; kk < 2; kk++) {
                    int col = (kk * 32 + l4 * 8) ^ ((row & 7) << 3);
                    bk[n][kk] = *(const bf16x8*)&Kl[row * 64 + col];
                }
            }

            f32x4 s[2][4];
#pragma unroll
            for (int m = 0; m < 2; m++)
#pragma unroll
                for (int n = 0; n < 4; n++)
#pragma unroll
                    for (int r = 0; r < 4; r++) s[m][n][r] = 0.0f;
            __builtin_amdgcn_s_setprio(1);
#pragma unroll
            for (int n = 0; n < 4; n++)
#pragma unroll
                for (int kk = 0; kk < 2; kk++)
#pragma unroll
                    for (int m = 0; m < 2; m++)
                        s[m][n] = mfma16(bk[n][kk], aq[m][kk], s[m][n]);
            __builtin_amdgcn_s_setprio(0);

            if (!allones) {
#pragma unroll
                for (int m = 0; m < 2; m++) {
                    int q = qt * 128 + wv * 32 + m * 16 + l15;
#pragma unroll
                    for (int n = 0; n < 4; n++)
#pragma unroll
                        for (int r = 0; r < 4; r++) {
                            int kg = kt * 128 + kh * 64 + (n >> 1) * 32 + l4 * 8 + (n & 1) * 4 + r;
                            if (mask[(size_t)q * SLEN + kg] == 0) s[m][n][r] = -1e20f;
                        }
                }
            }

            // exp2 -> pack P^T into K=32 B-frags (own-lane):
            // pb8[m][half][j] = p(k = half*32 + l4*8 + j), j = (n&1)*4 + r
            bf16x8 pb8[2][2];
#pragma unroll
            for (int m = 0; m < 2; m++)
#pragma unroll
                for (int half = 0; half < 2; half++)
#pragma unroll
                    for (int nn = 0; nn < 2; nn++)
#pragma unroll
                        for (int r = 0; r < 4; r++) {
                            float p = __builtin_amdgcn_exp2f(s[m][half * 2 + nn][r]);
                            lr[m] += p;
                            pb8[m][half][nn * 4 + r] = (__bf16)p;
                        }

            // V^T K=32 A-frags: row d = nd*16+l15, k = half*32 + l4*8 + j
            __builtin_amdgcn_s_setprio(1);
#pragma unroll
            for (int half = 0; half < 2; half++) {
#pragma unroll
                for (int nd = 0; nd < 4; nd++) {
                    int row = nd * 16 + l15;
                    int col = (half * 32 + l4 * 8) ^ ((row & 7) << 3);
                    bf16x8 av = *(const bf16x8*)&Vl[row * 64 + col];
#pragma unroll
                    for (int m = 0; m < 2; m++)
                        o[m][nd] = mfma16(av, pb8[m][half], o[m][nd]);
                }
            }
            __builtin_amdgcn_s_setprio(0);
        }

        __syncthreads();
        cur ^= 1;
    }

#pragma unroll
    for (int m = 0; m < 2; m++) {
        lr[m] += __shfl_xor(lr[m], 16);
        lr[m] += __shfl_xor(lr[m], 32);
    }

#pragma unroll
    for (int m = 0; m < 2; m++) {
        float inv = 1.0f / lr[m];
        int qrow = qt * 128 + wv * 32 + m * 16 + l15;
#pragma unroll
        for (int nd = 0; nd < 4; nd++) {
            bf16x4 ov;
#pragma unroll
            for (int r = 0; r < 4; r++) ov[r] = (__bf16)(o[m][nd][r] * inv);
            *(bf16x4*)(Attn + ((size_t)(qrow * BSZ + b)) * DMODEL + h * 64 + nd * 16 + l4 * 4) = ov;
        }
    }
}

// ---------------------------- launcher -------------------------------------
extern "C" void kernel_launch(void* const* d_in, const int* in_sizes, int n_in,
                              void* d_out, int out_size, void* d_ws, size_t ws_size,
                              hipStream_t stream) {
    const float* query  = (const float*)d_in[0];
    const float* keys   = (const float*)d_in[1];
    const float* values = (const float*)d_in[2];
    const int*   mask   = (const int*)d_in[3];
    const float* Wq     = (const float*)d_in[4];
    const float* Wk     = (const float*)d_in[5];
    const float* Wv     = (const float*)d_in[6];
    const float* Wo     = (const float*)d_in[7];
    float* out = (float*)d_out;

    char* ws = (char*)d_ws;
    const size_t MB = 1024 * 1024;
    __bf16* XQ   = (__bf16*)(ws + 0);
    __bf16* XK   = (__bf16*)(ws + 8 * MB);
    __bf16* XV   = (__bf16*)(ws + 16 * MB);
    __bf16* WCAT = (__bf16*)(ws + 24 * MB);   // [3072][1024]: Wq|Wk|Wv
    __bf16* WQB  = WCAT;
    __bf16* WKB  = (__bf16*)(ws + 26 * MB);
    __bf16* WVB  = (__bf16*)(ws + 28 * MB);
    __bf16* WOB  = (__bf16*)(ws + 30 * MB);
    __bf16* QKV  = (__bf16*)(ws + 32 * MB);   // [4096][3072] = 24 MB
    __bf16* VT   = (__bf16*)(ws + 0);         // reuse XQ (free after gemm_qkv)
    __bf16* ATT  = (__bf16*)(ws + 8 * MB);    // reuse XK
    unsigned int* flag = (unsigned int*)(ws + 56 * MB);

    (void)hipMemsetAsync(flag, 0xFF, 4, stream);

    const int NTOK = SLEN * BSZ;  // 4096
    const int NBIG = NTOK * DMODEL / 4, NW = DMODEL * DMODEL / 4;
    const float LOG2E = 1.4426950408889634f;
    CvtArgs ca;
    ca.src[0] = query;  ca.dst[0] = XQ;  ca.n4[0] = NBIG; ca.scale[0] = 1.0f;
    ca.src[1] = keys;   ca.dst[1] = XK;  ca.n4[1] = NBIG; ca.scale[1] = 1.0f;
    ca.src[2] = values; ca.dst[2] = XV;  ca.n4[2] = NBIG; ca.scale[2] = 1.0f;
    ca.src[3] = Wq;     ca.dst[3] = WQB; ca.n4[3] = NW;   ca.scale[3] = LOG2E;
    ca.src[4] = Wk;     ca.dst[4] = WKB; ca.n4[4] = NW;   ca.scale[4] = 1.0f;
    ca.src[5] = Wv;     ca.dst[5] = WVB; ca.n4[5] = NW;   ca.scale[5] = 1.0f;
    ca.src[6] = Wo;     ca.dst[6] = WOB; ca.n4[6] = NW;   ca.scale[6] = 1.0f;
    ca.mask = mask; ca.flag = flag; ca.maskn4 = SLEN * SLEN / 4;
    cvt_all<<<dim3(256, 8), 256, 0, stream>>>(ca);

    // fused QKV projection: grid (32, 24) = 768 blocks (128x128 single-buf)
    gemm_qkv<<<dim3(NTOK / 128, D3 / 128), 256, 0, stream>>>(XQ, XK, XV, WCAT, QKV);

    transpose_v<<<dim3(SLEN / 64, BSZ * NHEAD), 256, 0, stream>>>(QKV, VT);

    attn_fwd<<<BSZ * NHEAD * (SLEN / 128), 256, 0, stream>>>(QKV, VT, mask, flag, ATT);

    gemm_out<<<dim3(NTOK / 128, DMODEL / 64), 256, 0, stream>>>(ATT, WOB, out);
}

// Round 18
// 118.761 us; speedup vs baseline: 1.2658x; 1.0352x over previous
//
#include <hip/hip_runtime.h>

// ---------------------------------------------------------------------------
// MultiHeadAttention forward, MI355X (gfx950), bf16 MFMA pipeline. Round 18:
//  - transpose_v DELETED: gemm_qkv writes V directly in VT layout (bn>=16);
//    Q|K go to a [4096][2048] buffer (attn stride 2048).
//  - attn: R17 perm-K/K=32-PV structure + lr computed via ones-vector MFMA
//    (replaces 32 VALU adds/kh/wave + final shfl reduce).
//  - gemm_qkv: 128^2xBK64 single-buf. gemm_out: 128x64 dbuf.
// ---------------------------------------------------------------------------

typedef __attribute__((ext_vector_type(4))) float  f32x4;
typedef __attribute__((ext_vector_type(8))) __bf16 bf16x8;
typedef __attribute__((ext_vector_type(4))) __bf16 bf16x4;

#define SLEN 2048
#define BSZ  2
#define DMODEL 1024
#define NHEAD 16
#define DHEAD 64
#define D2 (2 * DMODEL)   // 2048 (Q|K buffer row)

__device__ __forceinline__ void async16(void* lds, const void* g) {
    __builtin_amdgcn_global_load_lds(
        (const __attribute__((address_space(1))) unsigned int*)g,
        (__attribute__((address_space(3))) unsigned int*)lds, 16, 0, 0);
}

__device__ __forceinline__ f32x4 mfma16(bf16x8 a, bf16x8 b, f32x4 c) {
    return __builtin_amdgcn_mfma_f32_16x16x32_bf16(a, b, c, 0, 0, 0);
}

// ------------------- fused convert fp32 -> bf16 (+ mask flag) --------------
struct CvtArgs {
    const float* src[7];
    __bf16* dst[7];
    int n4[7];
    float scale[7];
    const int* mask;
    unsigned int* flag;
    int maskn4;
};
__global__ void cvt_all(CvtArgs a) {
    const int t = blockIdx.y;
    const int stride = gridDim.x * blockDim.x;
    if (t == 7) {
        bool ok = true;
        for (int i = blockIdx.x * blockDim.x + threadIdx.x; i < a.maskn4; i += stride) {
            int4 v = ((const int4*)a.mask)[i];
            ok = ok && v.x && v.y && v.z && v.w;
        }
        if (!ok) atomicAnd(a.flag, 0u);
        return;
    }
    const float* __restrict__ src = a.src[t];
    __bf16* __restrict__ dst = a.dst[t];
    const int n4 = a.n4[t];
    const float sc = a.scale[t];
    for (int i = blockIdx.x * blockDim.x + threadIdx.x; i < n4; i += stride) {
        float4 v = ((const float4*)src)[i];
        bf16x4 o;
        o[0] = (__bf16)(v.x * sc); o[1] = (__bf16)(v.y * sc);
        o[2] = (__bf16)(v.z * sc); o[3] = (__bf16)(v.w * sc);
        ((bf16x4*)dst)[i] = o;
    }
}

// ------------------- gemm_qkv: 128x128xBK64, single-buf m97 loop -----------
// bn 0..15 -> QK[4096][2048]; bn 16..23 -> V written in VT layout.
__global__ __launch_bounds__(256, 3) void gemm_qkv(const __bf16* __restrict__ Xq,
                                                   const __bf16* __restrict__ Xk,
                                                   const __bf16* __restrict__ Xv,
                                                   const __bf16* __restrict__ W,
                                                   __bf16* __restrict__ QK,
                                                   __bf16* __restrict__ VT) {
    __shared__ __bf16 At[128 * 64];
    __shared__ __bf16 Bt[128 * 64];
    const int tid = threadIdx.x;
    const int lane = tid & 63, wv = tid >> 6;
    const int l15 = lane & 15, l4 = lane >> 4;
    const int wr = wv >> 1, wc = wv & 1;
    const int srow = lane >> 3;
    const int sbyte = (((lane & 7) ^ srow) << 4);
    const int bm = blockIdx.x, bn = blockIdx.y;
    const __bf16* A = (bn < 8) ? Xq : (bn < 16) ? Xk : Xv;
    const char* Ab = (const char*)(A + (size_t)bm * 128 * DMODEL);
    const char* Bb = (const char*)(W + (size_t)bn * 128 * DMODEL);

    f32x4 acc[4][4];
#pragma unroll
    for (int m = 0; m < 4; m++)
#pragma unroll
        for (int n = 0; n < 4; n++)
#pragma unroll
            for (int r = 0; r < 4; r++) acc[m][n][r] = 0.0f;

    for (int k0 = 0; k0 < DMODEL; k0 += 64) {
        __syncthreads();
#pragma unroll
        for (int i = 0; i < 8; i++) {
            int c = wv * 8 + i;
            if (c < 16) {
                int row = c * 8 + srow;
                async16(&At[c * 512], Ab + ((size_t)row * DMODEL + k0) * 2 + sbyte);
            } else {
                int row = (c - 16) * 8 + srow;
                async16(&Bt[(c - 16) * 512], Bb + ((size_t)row * DMODEL + k0) * 2 + sbyte);
            }
        }
        __syncthreads();

#pragma unroll
        for (int kk = 0; kk < 2; kk++) {
            bf16x8 af[4], bfr[4];
#pragma unroll
            for (int m = 0; m < 4; m++) {
                int row = wr * 64 + m * 16 + l15;
                int col = (kk * 32 + l4 * 8) ^ ((row & 7) << 3);
                af[m] = *(const bf16x8*)&At[row * 64 + col];
            }
#pragma unroll
            for (int n = 0; n < 4; n++) {
                int row = wc * 64 + n * 16 + l15;
                int col = (kk * 32 + l4 * 8) ^ ((row & 7) << 3);
                bfr[n] = *(const bf16x8*)&Bt[row * 64 + col];
            }
#pragma unroll
            for (int m = 0; m < 4; m++)
#pragma unroll
                for (int n = 0; n < 4; n++)
                    acc[m][n] = mfma16(af[m], bfr[n], acc[m][n]);
        }
    }

    if (bn < 16) {
#pragma unroll
        for (int m = 0; m < 4; m++)
#pragma unroll
            for (int n = 0; n < 4; n++)
#pragma unroll
                for (int r = 0; r < 4; r++) {
                    size_t row = (size_t)bm * 128 + wr * 64 + m * 16 + l4 * 4 + r;
                    size_t col = (size_t)bn * 128 + wc * 64 + n * 16 + l15;
                    QK[row * D2 + col] = (__bf16)acc[m][n][r];
                }
    } else {
        // V -> VT[((b*16+h)*64 + d)*2048 + s]; t=row: s=t>>1, b=t&1; hd=col-2048
#pragma unroll
        for (int m = 0; m < 4; m++)
#pragma unroll
            for (int n = 0; n < 4; n++)
#pragma unroll
                for (int r = 0; r < 4; r++) {
                    int t = bm * 128 + wr * 64 + m * 16 + l4 * 4 + r;
                    int hd = (bn - 16) * 128 + wc * 64 + n * 16 + l15;
                    int s = t >> 1, b = t & 1;
                    VT[((size_t)(b * NHEAD * DHEAD + hd)) * SLEN + s] = (__bf16)acc[m][n][r];
                }
    }
}

// ---------------------------- gemm_out: 128x64x64 dbuf ---------------------
__global__ __launch_bounds__(256, 2) void gemm_out(const __bf16* __restrict__ A,
                                                   const __bf16* __restrict__ B,
                                                   float* __restrict__ Cv) {
    __shared__ __bf16 At[2][128 * 64];
    __shared__ __bf16 Bt[2][64 * 64];
    const int tid = threadIdx.x;
    const int lane = tid & 63, wv = tid >> 6;
    const int l15 = lane & 15, l4 = lane >> 4;
    const int wr = wv >> 1, wc = wv & 1;
    const int srow = lane >> 3;
    const int sbyte = (((lane & 7) ^ srow) << 4);
    const int bm = blockIdx.x, bn = blockIdx.y;
    const char* Ab = (const char*)(A + (size_t)bm * 128 * DMODEL);
    const char* Bb = (const char*)(B + (size_t)bn * 64 * DMODEL);

    f32x4 acc[4][2];
#pragma unroll
    for (int m = 0; m < 4; m++)
#pragma unroll
        for (int n = 0; n < 2; n++)
#pragma unroll
            for (int r = 0; r < 4; r++) acc[m][n][r] = 0.0f;

    auto stage = [&](int buf, int k0) {
#pragma unroll
        for (int i = 0; i < 6; i++) {
            int c = wv * 6 + i;
            if (c < 16) {
                int row = c * 8 + srow;
                async16(&At[buf][c * 512], Ab + ((size_t)row * DMODEL + k0) * 2 + sbyte);
            } else {
                int row = (c - 16) * 8 + srow;
                async16(&Bt[buf][(c - 16) * 512], Bb + ((size_t)row * DMODEL + k0) * 2 + sbyte);
            }
        }
    };

    stage(0, 0);
    __syncthreads();
    int cur = 0;
    for (int k0 = 0; k0 < DMODEL; k0 += 64) {
        if (k0 + 64 < DMODEL) stage(cur ^ 1, k0 + 64);
#pragma unroll
        for (int kk = 0; kk < 2; kk++) {
            bf16x8 af[4], bfr[2];
#pragma unroll
            for (int m = 0; m < 4; m++) {
                int row = wr * 64 + m * 16 + l15;
                int col = (kk * 32 + l4 * 8) ^ ((row & 7) << 3);
                af[m] = *(const bf16x8*)&At[cur][row * 64 + col];
            }
#pragma unroll
            for (int n = 0; n < 2; n++) {
                int row = wc * 32 + n * 16 + l15;
                int col = (kk * 32 + l4 * 8) ^ ((row & 7) << 3);
                bfr[n] = *(const bf16x8*)&Bt[cur][row * 64 + col];
            }
#pragma unroll
            for (int m = 0; m < 4; m++)
#pragma unroll
                for (int n = 0; n < 2; n++)
                    acc[m][n] = mfma16(af[m], bfr[n], acc[m][n]);
        }
        __syncthreads();
        cur ^= 1;
    }

#pragma unroll
    for (int m = 0; m < 4; m++)
#pragma unroll
        for (int n = 0; n < 2; n++)
#pragma unroll
            for (int r = 0; r < 4; r++) {
                size_t row = (size_t)bm * 128 + wr * 64 + m * 16 + l4 * 4 + r;
                size_t col = (size_t)bn * 64 + wc * 32 + n * 16 + l15;
                Cv[row * DMODEL + col] = acc[m][n][r];
            }
}

// ---------------------------- attention (perm-K, K=32 PV, MFMA-lr) ---------
// grid 512; XCD swizzle. QBLK=128, KBLK=128 (2x64 halves), dbuf 64KB.
// K rows staged permuted: pi(p) = (p&32)+((p&12)<<1)+(((p>>4)&1)<<2)+(p&3).
// lr = ones-MFMA column sums (all lanes get the full row sum).
__global__ __launch_bounds__(256, 2) void attn_fwd(const __bf16* __restrict__ QK,
                                                   const __bf16* __restrict__ Vt,
                                                   const int* __restrict__ mask,
                                                   const unsigned int* __restrict__ flag,
                                                   __bf16* __restrict__ Attn) {
    __shared__ __bf16 Kt[2][2][64 * 64];
    __shared__ __bf16 Vs[2][2][64 * 64];
    const int tid = threadIdx.x;
    const int lane = tid & 63, wv = tid >> 6;
    const int l15 = lane & 15, l4 = lane >> 4;
    const int blk = blockIdx.x;
    const int xcd = blk & 7, idx = blk >> 3;
    const int bh = xcd + (idx >> 4) * 8;
    const int qt = idx & 15;
    const int b = bh >> 4, h = bh & 15;
    const bool allones = (*flag != 0u);
    const int srow = lane >> 3;
    const int sbyte = (((lane & 7) ^ srow) << 4);

    bf16x8 aq[2][2];
#pragma unroll
    for (int m = 0; m < 2; m++)
#pragma unroll
        for (int kk = 0; kk < 2; kk++) {
            int qrow = qt * 128 + wv * 32 + m * 16 + l15;
            aq[m][kk] = *(const bf16x8*)(QK + ((size_t)(qrow * BSZ + b) * D2 + h * 64 + kk * 32 + l4 * 8));
        }

    bf16x8 ones;
#pragma unroll
    for (int j = 0; j < 8; j++) ones[j] = (__bf16)1.0f;

    f32x4 o[2][4], olr[2];
#pragma unroll
    for (int m = 0; m < 2; m++) {
#pragma unroll
        for (int nd = 0; nd < 4; nd++)
#pragma unroll
            for (int r = 0; r < 4; r++) o[m][nd][r] = 0.0f;
#pragma unroll
        for (int r = 0; r < 4; r++) olr[m][r] = 0.0f;
    }

    const char* Kb = (const char*)QK + ((size_t)b * D2 + DMODEL + h * 64) * 2;
    const char* Vb = (const char*)Vt + ((size_t)bh * 64) * SLEN * 2;

    auto stage = [&](int buf, int kt) {
#pragma unroll
        for (int i = 0; i < 8; i++) {
            int c = wv * 8 + i;
            if (c < 16) {
                int kh = c >> 3, ck = c & 7;
                int p = (ck & 7) * 8 + srow;
                int kperm = (p & 32) + ((p & 12) << 1) + (((p >> 4) & 1) << 2) + (p & 3);
                int krow = kt * 128 + kh * 64 + kperm;
                async16(&Kt[buf][kh][ck * 512],
                        Kb + (size_t)krow * (BSZ * D2 * 2) + sbyte);
            } else {
                int c2 = c - 16;
                int kh = c2 >> 3, ck = c2 & 7;
                int drow = ck * 8 + srow;
                async16(&Vs[buf][kh][ck * 512],
                        Vb + (size_t)drow * (SLEN * 2) + kt * 256 + kh * 128 + sbyte);
            }
        }
    };

    stage(0, 0);
    __syncthreads();
    int cur = 0;

    for (int kt = 0; kt < SLEN / 128; kt++) {
        if (kt + 1 < SLEN / 128) stage(cur ^ 1, kt + 1);

#pragma unroll
        for (int kh = 0; kh < 2; kh++) {
            const __bf16* Kl = Kt[cur][kh];
            const __bf16* Vl = Vs[cur][kh];

            bf16x8 bk[4][2];
#pragma unroll
            for (int n = 0; n < 4; n++) {
                int row = n * 16 + l15;
#pragma unroll
                for (int kk = 0; kk < 2; kk++) {
                    int col = (kk * 32 + l4 * 8) ^ ((row & 7) << 3);
                    bk[n][kk] = *(const bf16x8*)&Kl[row * 64 + col];
                }
            }

            f32x4 s[2][4];
#pragma unroll
            for (int m = 0; m < 2; m++)
#pragma unroll
                for (int n = 0; n < 4; n++)
#pragma unroll
                    for (int r = 0; r < 4; r++) s[m][n][r] = 0.0f;
            __builtin_amdgcn_s_setprio(1);
#pragma unroll
            for (int n = 0; n < 4; n++)
#pragma unroll
                for (int kk = 0; kk < 2; kk++)
#pragma unroll
                    for (int m = 0; m < 2; m++)
                        s[m][n] = mfma16(bk[n][kk], aq[m][kk], s[m][n]);
            __builtin_amdgcn_s_setprio(0);

            if (!allones) {
#pragma unroll
                for (int m = 0; m < 2; m++) {
                    int q = qt * 128 + wv * 32 + m * 16 + l15;
#pragma unroll
                    for (int n = 0; n < 4; n++)
#pragma unroll
                        for (int r = 0; r < 4; r++) {
                            int kg = kt * 128 + kh * 64 + (n >> 1) * 32 + l4 * 8 + (n & 1) * 4 + r;
                            if (mask[(size_t)q * SLEN + kg] == 0) s[m][n][r] = -1e20f;
                        }
                }
            }

            // exp2 -> pack P^T into K=32 B-frags (own-lane)
            bf16x8 pb8[2][2];
#pragma unroll
            for (int m = 0; m < 2; m++)
#pragma unroll
                for (int half = 0; half < 2; half++)
#pragma unroll
                    for (int nn = 0; nn < 2; nn++)
#pragma unroll
                        for (int r = 0; r < 4; r++) {
                            float p = __builtin_amdgcn_exp2f(s[m][half * 2 + nn][r]);
                            pb8[m][half][nn * 4 + r] = (__bf16)p;
                        }

            __builtin_amdgcn_s_setprio(1);
#pragma unroll
            for (int half = 0; half < 2; half++) {
#pragma unroll
                for (int nd = 0; nd < 4; nd++) {
                    int row = nd * 16 + l15;
                    int col = (half * 32 + l4 * 8) ^ ((row & 7) << 3);
                    bf16x8 av = *(const bf16x8*)&Vl[row * 64 + col];
#pragma unroll
                    for (int m = 0; m < 2; m++)
                        o[m][nd] = mfma16(av, pb8[m][half], o[m][nd]);
                }
#pragma unroll
                for (int m = 0; m < 2; m++)
                    olr[m] = mfma16(ones, pb8[m][half], olr[m]);
            }
            __builtin_amdgcn_s_setprio(0);
        }

        __syncthreads();
        cur ^= 1;
    }

    // olr rows are all the full column sum -> no cross-lane reduce needed
#pragma unroll
    for (int m = 0; m < 2; m++) {
        float inv = 1.0f / olr[m][0];
        int qrow = qt * 128 + wv * 32 + m * 16 + l15;
#pragma unroll
        for (int nd = 0; nd < 4; nd++) {
            bf16x4 ov;
#pragma unroll
            for (int r = 0; r < 4; r++) ov[r] = (__bf16)(o[m][nd][r] * inv);
            *(bf16x4*)(Attn + ((size_t)(qrow * BSZ + b)) * DMODEL + h * 64 + nd * 16 + l4 * 4) = ov;
        }
    }
}

// ---------------------------- launcher -------------------------------------
extern "C" void kernel_launch(void* const* d_in, const int* in_sizes, int n_in,
                              void* d_out, int out_size, void* d_ws, size_t ws_size,
                              hipStream_t stream) {
    const float* query  = (const float*)d_in[0];
    const float* keys   = (const float*)d_in[1];
    const float* values = (const float*)d_in[2];
    const int*   mask   = (const int*)d_in[3];
    const float* Wq     = (const float*)d_in[4];
    const float* Wk     = (const float*)d_in[5];
    const float* Wv     = (const float*)d_in[6];
    const float* Wo     = (const float*)d_in[7];
    float* out = (float*)d_out;

    char* ws = (char*)d_ws;
    const size_t MB = 1024 * 1024;
    __bf16* XQ   = (__bf16*)(ws + 0);
    __bf16* XK   = (__bf16*)(ws + 8 * MB);
    __bf16* XV   = (__bf16*)(ws + 16 * MB);
    __bf16* WCAT = (__bf16*)(ws + 24 * MB);   // [3072][1024]: Wq|Wk|Wv
    __bf16* WQB  = WCAT;
    __bf16* WKB  = (__bf16*)(ws + 26 * MB);
    __bf16* WVB  = (__bf16*)(ws + 28 * MB);
    __bf16* WOB  = (__bf16*)(ws + 30 * MB);
    __bf16* QKB  = (__bf16*)(ws + 32 * MB);   // [4096][2048] Q|K = 16 MB
    __bf16* VT   = (__bf16*)(ws + 48 * MB);   // [2048][2048]-ish V^T = 8 MB
    __bf16* ATT  = (__bf16*)(ws + 8 * MB);    // reuse XK (free after gemm_qkv)
    unsigned int* flag = (unsigned int*)(ws + 56 * MB);

    (void)hipMemsetAsync(flag, 0xFF, 4, stream);

    const int NTOK = SLEN * BSZ;  // 4096
    const int NBIG = NTOK * DMODEL / 4, NW = DMODEL * DMODEL / 4;
    const float LOG2E = 1.4426950408889634f;
    CvtArgs ca;
    ca.src[0] = query;  ca.dst[0] = XQ;  ca.n4[0] = NBIG; ca.scale[0] = 1.0f;
    ca.src[1] = keys;   ca.dst[1] = XK;  ca.n4[1] = NBIG; ca.scale[1] = 1.0f;
    ca.src[2] = values; ca.dst[2] = XV;  ca.n4[2] = NBIG; ca.scale[2] = 1.0f;
    ca.src[3] = Wq;     ca.dst[3] = WQB; ca.n4[3] = NW;   ca.scale[3] = LOG2E;
    ca.src[4] = Wk;     ca.dst[4] = WKB; ca.n4[4] = NW;   ca.scale[4] = 1.0f;
    ca.src[5] = Wv;     ca.dst[5] = WVB; ca.n4[5] = NW;   ca.scale[5] = 1.0f;
    ca.src[6] = Wo;     ca.dst[6] = WOB; ca.n4[6] = NW;   ca.scale[6] = 1.0f;
    ca.mask = mask; ca.flag = flag; ca.maskn4 = SLEN * SLEN / 4;
    cvt_all<<<dim3(256, 8), 256, 0, stream>>>(ca);

    // fused QKV projection + V-transpose: grid (32, 24)
    gemm_qkv<<<dim3(NTOK / 128, 3 * DMODEL / 128), 256, 0, stream>>>(XQ, XK, XV, WCAT, QKB, VT);

    attn_fwd<<<BSZ * NHEAD * (SLEN / 128), 256, 0, stream>>>(QKB, VT, mask, flag, ATT);

    gemm_out<<<dim3(NTOK / 128, DMODEL / 64), 256, 0, stream>>>(ATT, WOB, out);
}